// Round 3
// baseline (2638.579 us; speedup 1.0000x reference)
//
#include <hip/hip_runtime.h>
#include <hip/hip_bf16.h>
#include <stdint.h>

// ---------------------------------------------------------------------------
// SparseDecoderWave — MFMA bf16 implicit-GEMM, 3-segment K-stacked split.
// K layout per conv: [A_hi | A_lo | A_hi] x [W_hi | W_hi | W_lo]  (SEG=3)
//   => ah*wh + al*wh + ah*wl  (full double-bf16 cross terms, err ~2^-16).
// up3 is single-bf16 (SEG=1).
// Staging: T3 2-phase async — double-buffered LDS, global_load_lds (16B),
//   one barrier per k-chunk. XOR slot swizzle applied on the GLOBAL source
//   permutation (linear LDS dest, rule: gload_lds writes base+lane*16);
//   reads keep the swizzled addressing (bank-conflict-free, measured 0).
// Masked (MODE 2) / pad lanes redirect src address to a 16KB zero page.
// R2 fix: W-staging ocl used & (NOC-1) — wrong for stem NOC=48 (not pow2).
// ---------------------------------------------------------------------------

typedef float f32x4 __attribute__((ext_vector_type(4)));
typedef short s16x8 __attribute__((ext_vector_type(8)));

typedef const __attribute__((address_space(1))) void* gas_ptr;
typedef __attribute__((address_space(3))) void* las_ptr;

__device__ __forceinline__ void gl_lds16(const void* g, void* l) {
    __builtin_amdgcn_global_load_lds((gas_ptr)g, (las_ptr)l, 16, 0, 0);
}

__device__ __forceinline__ ushort f2bf(float f) {
    uint32_t u = __float_as_uint(f);
    u += 0x7FFFu + ((u >> 16) & 1u);
    return (ushort)(u >> 16);
}
__device__ __forceinline__ float bf2f(ushort h) {
    return __uint_as_float(((uint32_t)h) << 16);
}

// ---- zero page + XD0 head guard init (idempotent, runs each launch) ----
__global__ __launch_bounds__(256)
void zero_k(ushort* __restrict__ zp, ushort* __restrict__ xd0head)
{
    const int t = threadIdx.x;
    const uint4 z = {0, 0, 0, 0};
    for (int i = t; i < 1024; i += 256) *(uint4*)(zp + i * 8) = z;  // 16 KB
    if (t < 16) *(uint4*)(xd0head + t * 8) = z;                     // 256 B
}

// ---- weight repack: w[oc][ct][3][3] fp32 -> W'[t][OCP][KT] bf16 ----
__global__ __launch_bounds__(256)
void repack_w_k(const float* __restrict__ w, ushort* __restrict__ out,
                int OC, int CT, int ICOFF, int CAR, int CAP, int CAT,
                int CBR, int CBP, int SEG, int OCP, int KT)
{
    const int KG = KT / 8;
    const int u = blockIdx.x * 256 + threadIdx.x;
    if (u >= OCP * KG) return;
    const int oc = u / KG, kg = u - oc * KG;
    const int k0 = kg * 8;
    int ic, lo; bool ok;
    if (k0 < SEG * CAP) {
        const int seg = k0 / CAP, c = k0 - seg * CAP;
        lo = (seg == 2); ic = ICOFF + c; ok = (c < CAR);
    } else {
        const int kb = k0 - SEG * CAP;
        const int seg = kb / CBP, c = kb - seg * CBP;
        lo = (seg == 2); ic = CAT + c; ok = (c < CBR);
    }
    ok = ok && (oc < OC);
    for (int t = 0; t < 9; ++t) {
        ushort q[8];
#pragma unroll
        for (int j = 0; j < 8; ++j) q[j] = 0;
        if (ok) {
#pragma unroll
            for (int j = 0; j < 8; ++j) {
                const float v = w[((size_t)oc * CT + ic + j) * 9 + t];
                const ushort h = f2bf(v);
                q[j] = lo ? f2bf(v - bf2f(h)) : h;
            }
        }
        *(uint4*)(out + ((size_t)t * OCP + oc) * KT + k0) = *(uint4*)q;
    }
}

// ---- input repack: [b][c][p] fp32 -> [b][p][OST] bf16 hi(+lo at LOOFF) ----
template<bool SPLIT>
__global__ __launch_bounds__(256)
void repack_x_k(const float* __restrict__ in, ushort* __restrict__ out,
                int C, int HW, int OST, int LOOFF)
{
    __shared__ float tile[32][65];
    const int b = blockIdx.z, c0 = blockIdx.y * 32, p0 = blockIdx.x * 64;
    for (int e = threadIdx.x; e < 2048; e += 256) {
        const int cl = e >> 6, pl = e & 63;
        tile[cl][pl] = in[((size_t)b * C + c0 + cl) * HW + p0 + pl];
    }
    __syncthreads();
    const int pl = threadIdx.x >> 2, cg = (threadIdx.x & 3) * 8;
    ushort hv[8], lv[8];
#pragma unroll
    for (int j = 0; j < 8; ++j) {
        const float v = tile[cg + j][pl];
        const ushort h = f2bf(v);
        hv[j] = h;
        lv[j] = f2bf(v - bf2f(h));
    }
    const size_t o = ((size_t)b * HW + p0 + pl) * OST + c0 + cg;
    *(uint4*)(out + o) = *(uint4*)hv;
    if constexpr (SPLIT) *(uint4*)(out + LOOFF + o) = *(uint4*)lv;
}

// ---- async MFMA conv3x3: double-buffered LDS, global_load_lds staging ----
// MODE 0: edge pad (stem); MODE 1: reflect, A up2x (up1);
// MODE 2: reflect, A up2x, mask-redirected staging + leaky*wvm epilogue.
template<int MODE, int WR, int WC, int WROWS, int WCOLF, int NOCF,
         int H, int W, int OCP, int KT, int CAP, int CBP, int SEG,
         int ASTR, int APLSTR, int AOFF, int BSTR, int KS,
         bool SOUT, bool ACCIN>
__global__ __launch_bounds__(256, 2)
void conv_async_k(const ushort* __restrict__ xA, const ushort* __restrict__ xB,
                  const ushort* __restrict__ wgt, const float* __restrict__ bias,
                  const float* __restrict__ upm, const float* __restrict__ cam,
                  const float* __restrict__ wvm, const ushort* __restrict__ zpad,
                  ushort* __restrict__ outb, float* __restrict__ outp, int OC)
{
    constexpr int BROWS = WR * WROWS;
    constexpr int BCOLS = WC * WCOLF * 16;
    constexpr int NOC = NOCF * 16;
    constexpr int PH = BROWS + 2, PW = BCOLS + 2;
    constexpr int NPX = PH * PW;
    constexpr int NAU = NPX * 4;                    // A 16B slots
    constexpr int ASL = ((NAU + 63) / 64) * 64;     // wave-padded
    constexpr int NWU = 9 * NOC * 4;                // W 16B slots (mult of 64)
    constexpr int NSA = (ASL + 255) / 256;
    constexpr int NSW = (NWU + 255) / 256;
    constexpr int PERBUF = (ASL + NWU) * 8;         // ushorts per buffer
    constexpr int NCH = KT / 32;
    constexpr int XT = W / BCOLS;
    constexpr int HP = ((H + BROWS - 1) / BROWS) * BROWS;
    constexpr int HA = (MODE == 0) ? H : H / 2;
    constexpr int WA = (MODE == 0) ? W : W / 2;
    constexpr bool HASB = (SEG * CAP < KT);

    __shared__ __align__(16) ushort lds[2 * PERBUF];

    const int tid = threadIdx.x;
    const int b = blockIdx.z / KS, sid = blockIdx.z % KS;
    const int oc0 = blockIdx.y * NOC;
    const int y0 = (blockIdx.x / XT) * BROWS;
    const int x0 = (blockIdx.x % XT) * BCOLS;
    const int lane = tid & 63, wv = tid >> 6;
    const int wr = wv / WC, wc = wv % WC;
    const int lq = lane >> 4, ln = lane & 15;
    const int wcb = wc * (WCOLF * 16);
    const int c0 = (sid * NCH) / KS, c1 = ((sid + 1) * NCH) / KS;
    const int wbv = wv * 512;                       // wave slot base (ushorts)

    // ---- A staging geometry (k-independent, source-permuted by swizzle) ----
    const ushort* pAp[NSA]; const ushort* pBp[NSA]; int aKO[NSA];
    for (int s = 0; s < NSA; ++s) {
        const int u = tid + s * 256;
        const int pp = u >> 2, sl = u & 3;
        aKO[s] = (sl ^ ((pp >> 1) & 3)) * 8;        // pre-swizzled k-group
        const bool val = pp < NPX;
        const int ppc = val ? pp : 0;
        const int py = ppc / PW, px = ppc - py * PW;
        int y = y0 + py - 1, x = x0 + px - 1;
        if (MODE == 0) { y = min(max(y, 0), H - 1); x = min(max(x, 0), W - 1); }
        else { y = (y < 0) ? -y : ((y >= H) ? 2 * H - 2 - y : y);
               x = (x < 0) ? -x : ((x >= W) ? 2 * W - 2 - x : x); }
        const int ya = (MODE == 0) ? y : (y >> 1);
        const int xa = (MODE == 0) ? x : (x >> 1);
        bool okA = val, okB = val;
        if (MODE == 2) {
            const float cm = cam[((size_t)b * H + y) * W + x];
            const float um = upm[((size_t)b * HA + ya) * WA + xa];
            okA = okA && (um * cm != 0.f);
            okB = okB && (cm != 0.f);
        }
        pAp[s] = okA ? xA + (size_t)((b * HA + ya) * WA + xa) * ASTR : zpad;
        if constexpr (HASB)
            pBp[s] = okB ? xB + (size_t)((b * H + y) * W + x) * BSTR : zpad;
        else
            pBp[s] = zpad;
    }
    // ---- W staging geometry ----
    const ushort* pWp[NSW];
    for (int s = 0; s < NSW; ++s) {
        const int u = tid + s * 256;
        const int wrow = u >> 2, sl = u & 3;
        const int kg = sl ^ ((wrow >> 1) & 3);      // pre-swizzled k-group
        const int t = wrow / NOC, ocl = wrow - t * NOC;  // R2 fix: true modulo
        pWp[s] = (u < NWU) ?
            wgt + (size_t)(t * OCP + oc0 + ocl) * KT + kg * 8 : zpad;
    }

    auto stage = [&](int buf, int kc) {
        ushort* ab = lds + buf * PERBUF;
        ushort* wb = ab + ASL * 8;
        const int ko = kc * 32;
#pragma unroll
        for (int s = 0; s < NSA; ++s) {
            if (s * 256 + wv * 64 < NAU) {          // wave-uniform skip
                const int k = ko + aKO[s];
                const ushort* g;
                if (!HASB || k < SEG * CAP) {
                    int ka = (SEG == 3 && k >= 2 * CAP) ? k - 2 * CAP : k;
                    const int pl = (ka >= CAP) ? 1 : 0;
                    g = pAp[s] + pl * APLSTR + AOFF + (ka - pl * CAP);
                } else {
                    int kb = k - SEG * CAP;
                    if (SEG == 3 && kb >= 2 * CBP) kb -= 2 * CBP;
                    g = pBp[s] + kb;
                }
                gl_lds16(g, ab + s * 2048 + wbv);
            }
        }
#pragma unroll
        for (int s = 0; s < NSW; ++s)
            if (s * 256 + wv * 64 < NWU)            // wave-uniform skip
                gl_lds16(pWp[s] + ko, wb + s * 2048 + wbv);
    };

    f32x4 acc[WROWS][WCOLF][NOCF];
#pragma unroll
    for (int i = 0; i < WROWS; ++i)
#pragma unroll
        for (int c = 0; c < WCOLF; ++c)
#pragma unroll
            for (int n = 0; n < NOCF; ++n) acc[i][c][n] = {0.f, 0.f, 0.f, 0.f};

    if (ACCIN) {
#pragma unroll
        for (int ri = 0; ri < WROWS; ++ri) {
            const float* Pr = outp +
                ((((size_t)sid * 4 + b) * HP + y0 + wr * WROWS + ri) * W + x0 + wcb) * OCP;
#pragma unroll
            for (int cf = 0; cf < WCOLF; ++cf)
#pragma unroll
                for (int n2 = 0; n2 < NOCF; ++n2)
#pragma unroll
                    for (int r = 0; r < 4; ++r)
                        acc[ri][cf][n2][r] =
                            Pr[(size_t)(cf * 16 + lq * 4 + r) * OCP + oc0 + n2 * 16 + ln];
        }
    }

    stage(0, c0);
    __syncthreads();                                 // vmcnt drain: buf0 ready
    int cur = 0;
    for (int kc = c0; kc < c1; ++kc) {
        if (kc + 1 < c1) stage(cur ^ 1, kc + 1);     // async into other buffer
        const ushort* at = lds + cur * PERBUF;
        const ushort* wt = at + ASL * 8;
        // ---- preload A fragments (swizzled reads, conflict-free) ----
        s16x8 afr[WROWS + 2][WCOLF][3];
#pragma unroll
        for (int ar = 0; ar < WROWS + 2; ++ar)
#pragma unroll
            for (int cf = 0; cf < WCOLF; ++cf)
#pragma unroll
                for (int dx = 0; dx < 3; ++dx) {
                    const int p = (wr * WROWS + ar) * PW + wcb + cf * 16 + ln + dx;
                    afr[ar][cf][dx] = *(const s16x8*)
                        &at[p * 32 + ((lq ^ ((p >> 1) & 3)) * 8)];
                }
        // ---- 9 taps ----
#pragma unroll
        for (int t = 0; t < 9; ++t) {
            const int dy = t / 3, dx = t - dy * 3;
#pragma unroll
            for (int n2 = 0; n2 < NOCF; ++n2) {
                const int wrow = t * NOC + n2 * 16 + ln;
                const s16x8 bw = *(const s16x8*)
                    &wt[wrow * 32 + ((lq ^ ((wrow >> 1) & 3)) * 8)];
#pragma unroll
                for (int ri = 0; ri < WROWS; ++ri)
#pragma unroll
                    for (int cf = 0; cf < WCOLF; ++cf)
                        acc[ri][cf][n2] = __builtin_amdgcn_mfma_f32_16x16x32_bf16(
                            afr[ri + dy][cf][dx], bw, acc[ri][cf][n2], 0, 0, 0);
            }
        }
        __syncthreads();   // drains lgkm (reads done) + vmcnt (next buf staged)
        cur ^= 1;
    }

    // ---- epilogue ----
    if (KS > 1) {
#pragma unroll
        for (int ri = 0; ri < WROWS; ++ri) {
            float* Pr = outp +
                ((((size_t)sid * 4 + b) * HP + y0 + wr * WROWS + ri) * W + x0 + wcb) * OCP;
#pragma unroll
            for (int cf = 0; cf < WCOLF; ++cf)
#pragma unroll
                for (int n2 = 0; n2 < NOCF; ++n2)
#pragma unroll
                    for (int r = 0; r < 4; ++r)
                        Pr[(size_t)(cf * 16 + lq * 4 + r) * OCP + oc0 + n2 * 16 + ln] =
                            acc[ri][cf][n2][r];
        }
    } else {
        constexpr int OST = SOUT ? 2 * OCP : OCP;
#pragma unroll
        for (int ri = 0; ri < WROWS; ++ri) {
            const int y = y0 + wr * WROWS + ri;
#pragma unroll
            for (int cf = 0; cf < WCOLF; ++cf)
#pragma unroll
                for (int n2 = 0; n2 < NOCF; ++n2) {
                    const int oc = oc0 + n2 * 16 + ln;
                    const float bv = (oc < OC) ? bias[oc] : 0.f;
#pragma unroll
                    for (int r = 0; r < 4; ++r) {
                        const int x = x0 + wcb + cf * 16 + lq * 4 + r;
                        float v = acc[ri][cf][n2][r] + bv;
                        v = v > 0.f ? v : 0.2f * v;
                        v *= wvm[((size_t)b * H + y) * W + x];
                        if (oc >= OC) v = 0.f;
                        const size_t o = (((size_t)b * H + y) * W + x) * OST + oc;
                        const ushort h = f2bf(v);
                        outb[o] = h;
                        if constexpr (SOUT) outb[o + OCP] = f2bf(v - bf2f(h));
                    }
                }
        }
    }
}

// ---- split-K reduce: sum fp32 partials, bias(+leaky), bf16 hi/lo store ----
template<int KS, int HP, int H, int W, int OCP, bool ACT>
__global__ __launch_bounds__(256)
void reduce_k(const float* __restrict__ P, const float* __restrict__ bias,
              ushort* __restrict__ out, int OC)
{
    constexpr int OG = OCP / 4;
    const int u = blockIdx.x * 256 + threadIdx.x;
    if (u >= 4 * H * W * OG) return;
    const int og = u % OG;
    const int px = u / OG;
    const int x = px % W, y = (px / W) % H, b = px / (W * H);
    float4 s = {0.f, 0.f, 0.f, 0.f};
    for (int sid = 0; sid < KS; ++sid) {
        const float4 v = *(const float4*)
            (P + ((((size_t)sid * 4 + b) * HP + y) * W + x) * OCP + og * 4);
        s.x += v.x; s.y += v.y; s.z += v.z; s.w += v.w;
    }
    const int oc = og * 4;
    const float vv[4] = {s.x, s.y, s.z, s.w};
    ushort hi[4], lo[4];
#pragma unroll
    for (int j = 0; j < 4; ++j) {
        float v = (oc + j < OC) ? vv[j] + bias[oc + j] : 0.f;
        if (ACT) v = v > 0.f ? v : 0.2f * v;
        const ushort h = f2bf(v);
        hi[j] = h;
        lo[j] = f2bf(v - bf2f(h));
    }
    const size_t o = (size_t)px * 2 * OCP + oc;
    *(uint2*)(out + o) = *(uint2*)hi;
    *(uint2*)(out + o + OCP) = *(uint2*)lo;
}

// ---- wave weight repack: wh[3][C][9](+wll[C][9]) -> Wv[t][CP][4] fp32 ----
__global__ __launch_bounds__(256)
void repack_wv_k(const float* __restrict__ wh, const float* __restrict__ wll,
                 float* __restrict__ out, int C, int CP)
{
    const int u = blockIdx.x * 256 + threadIdx.x;
    if (u >= 9 * CP) return;
    const int t = u / CP, ic = u - t * CP;
    float4 v = {0.f, 0.f, 0.f, 0.f};
    if (ic < C) {
        v.x = wh[((size_t)0 * C + ic) * 9 + t];
        v.y = wh[((size_t)1 * C + ic) * 9 + t];
        v.z = wh[((size_t)2 * C + ic) * 9 + t];
        if (wll) v.w = wll[(size_t)ic * 9 + t];
    }
    *(float4*)(out + (size_t)u * 4) = v;
}

// ---- wave convs from channel-last bf16 (hi at +0, lo at +LOOFF) ----
template<int G, int CSTR, int LOOFF, int H, int W, bool SIN, bool HAS_LL>
__global__ __launch_bounds__(256)
void wave_cl_k(const ushort* __restrict__ xq, const float* __restrict__ wv,
               const float* __restrict__ bh, const float* __restrict__ bll,
               const float* __restrict__ mhalf, float scale,
               float* __restrict__ outh, float* __restrict__ outll)
{
    const int lane = threadIdx.x & 63;
    const int pix = blockIdx.x * 4 + (threadIdx.x >> 6);
    const int x = pix % W, y = (pix / W) % H, b = pix / (W * H);
    float a0 = 0.f, a1 = 0.f, a2 = 0.f, a3 = 0.f;
    for (int it = lane; it < 9 * G; it += 64) {
        const int t = it / G, g = it - t * G;
        const int dy = t / 3 - 1, dx = t % 3 - 1;
        const int yy = y + dy, xx = x + dx;
        const int yc = min(max(yy, 0), H - 1), xc = min(max(xx, 0), W - 1);
        const bool inr = (yy >= 0) && (yy < H) && (xx >= 0) && (xx < W);
        const size_t base = (((size_t)b * H + yc) * W + xc) * CSTR + g * 8;
        const uint4 hv = *(const uint4*)(xq + base);
        uint4 lv = {0, 0, 0, 0};
        if constexpr (!SIN) lv = *(const uint4*)(xq + base + LOOFF);
        const float4* wp = (const float4*)(wv + ((size_t)t * (G * 8) + g * 8) * 4);
        const uint* hw = (const uint*)&hv;
        const uint* lw = (const uint*)&lv;
#pragma unroll
        for (int j = 0; j < 8; ++j) {
            const uint wd = hw[j >> 1];
            float xf = (j & 1) ? __uint_as_float(wd & 0xFFFF0000u)
                               : __uint_as_float(wd << 16);
            if constexpr (!SIN) {
                const uint wl = lw[j >> 1];
                xf += (j & 1) ? __uint_as_float(wl & 0xFFFF0000u)
                              : __uint_as_float(wl << 16);
            }
            const float xz = inr ? xf : 0.f;
            const float4 w4 = wp[j];
            a0 = fmaf(w4.x, xz, a0);
            a1 = fmaf(w4.y, xz, a1);
            a2 = fmaf(w4.z, xz, a2);
            if constexpr (HAS_LL) a3 = fmaf(w4.w, xf, a3);
        }
    }
#pragma unroll
    for (int o = 1; o < 64; o <<= 1) {
        a0 += __shfl_xor(a0, o);
        a1 += __shfl_xor(a1, o);
        a2 += __shfl_xor(a2, o);
        if constexpr (HAS_LL) a3 += __shfl_xor(a3, o);
    }
    if (lane == 0) {
        float wm = 1.f;
        if (mhalf) wm = mhalf[((size_t)b * (H / 2) + (y >> 1)) * (W / 2) + (x >> 1)];
        const size_t hb = (size_t)b * 3 * H * W + (size_t)y * W + x;
        outh[hb]             = (a0 + bh[0]) * scale * wm;
        outh[hb + H * W]     = (a1 + bh[1]) * scale * wm;
        outh[hb + 2 * H * W] = (a2 + bh[2]) * scale * wm;
        if constexpr (HAS_LL) outll[((size_t)b * H + y) * W + x] = (a3 + bll[0]) * 8.f;
    }
}

// ---- inverse Haar DWT ----
template<int H, int W>
__global__ __launch_bounds__(256)
void idwt_k(const float* __restrict__ ll, const float* __restrict__ h,
            float* __restrict__ out)
{
    const int g = blockIdx.x * 256 + threadIdx.x;
    if (g >= 4 * H * W) return;
    const int x = g % W, y = (g / W) % H, b = g / (W * H);
    const float l  = ll[g];
    const float lh = h[((size_t)(b * 3 + 0) * H + y) * W + x];
    const float hl = h[((size_t)(b * 3 + 1) * H + y) * W + x];
    const float hh = h[((size_t)(b * 3 + 2) * H + y) * W + x];
    const float x00 = (l + lh + hl + hh) * 0.5f;
    const float x01 = (l - lh + hl - hh) * 0.5f;
    const float x10 = (l + lh - hl - hh) * 0.5f;
    const float x11 = (l - lh - hl + hh) * 0.5f;
    float* ob = out + (size_t)b * (2 * H) * (2 * W);
    ob[(size_t)(2 * y) * (2 * W) + 2 * x]         = x00;
    ob[(size_t)(2 * y) * (2 * W) + 2 * x + 1]     = x01;
    ob[(size_t)(2 * y + 1) * (2 * W) + 2 * x]     = x10;
    ob[(size_t)(2 * y + 1) * (2 * W) + 2 * x + 1] = x11;
}

__global__ __launch_bounds__(256)
void minmax_k(const float* __restrict__ p, int n, float* __restrict__ thr)
{
    __shared__ float smax[256], smin[256];
    float mx = -1e30f, mn = 1e30f;
    for (int i = threadIdx.x; i < n; i += 256) {
        const float v = p[i];
        mx = fmaxf(mx, v);
        mn = fminf(mn, v);
    }
    smax[threadIdx.x] = mx;
    smin[threadIdx.x] = mn;
    __syncthreads();
    for (int s = 128; s > 0; s >>= 1) {
        if (threadIdx.x < s) {
            smax[threadIdx.x] = fmaxf(smax[threadIdx.x], smax[threadIdx.x + s]);
            smin[threadIdx.x] = fminf(smin[threadIdx.x], smin[threadIdx.x + s]);
        }
        __syncthreads();
    }
    if (threadIdx.x == 0) *thr = (smax[0] - smin[0]) * 0.1f;
}

template<int H, int W>
__global__ __launch_bounds__(256)
void mask_k(const float* __restrict__ h, const float* __restrict__ thr,
            float* __restrict__ mask)
{
    const int g = blockIdx.x * 256 + threadIdx.x;
    if (g >= 4 * H * W) return;
    const int x = g % W, y = (g / W) % H, b = g / (W * H);
    const float t  = *thr;
    const float v0 = fabsf(h[((size_t)(b * 3 + 0) * H + y) * W + x]);
    const float v1 = fabsf(h[((size_t)(b * 3 + 1) * H + y) * W + x]);
    const float v2 = fabsf(h[((size_t)(b * 3 + 2) * H + y) * W + x]);
    mask[g] = (fmaxf(v0, fmaxf(v1, v2)) > t) ? 1.f : 0.f;
}

template<int H, int W, int R>
__global__ __launch_bounds__(256)
void dilate_k(const float* __restrict__ m, float* __restrict__ o)
{
    const int g = blockIdx.x * 256 + threadIdx.x;
    if (g >= 4 * H * W) return;
    const int x = g % W, y = (g / W) % H, b = g / (W * H);
    float v = 0.f;
    for (int dy = -R; dy <= R; ++dy) {
        const int yy = y + dy;
        if (yy < 0 || yy >= H) continue;
        for (int dx = -R; dx <= R; ++dx) {
            const int xx = x + dx;
            if (xx < 0 || xx >= W) continue;
            v = fmaxf(v, m[((size_t)b * H + yy) * W + xx]);
        }
    }
    o[g] = (v > 0.f) ? 1.f : 0.f;
}

template<int H, int W>
__global__ __launch_bounds__(256)
void masksfull_k(const float* __restrict__ m, float* __restrict__ conva,
                 float* __restrict__ wavem)
{
    const int g = blockIdx.x * 256 + threadIdx.x;
    constexpr int H2 = 2 * H, W2 = 2 * W;
    if (g >= 4 * H2 * W2) return;
    const int x = g % W2, y = (g / W2) % H2, b = g / (W2 * H2);
    float c5 = 0.f, c3 = 0.f;
    for (int dy = -2; dy <= 2; ++dy) {
        const int yy = y + dy;
        if (yy < 0 || yy >= H2) continue;
        const int my = yy >> 1;
        for (int dx = -2; dx <= 2; ++dx) {
            const int xx = x + dx;
            if (xx < 0 || xx >= W2) continue;
            const float v = m[((size_t)b * H + my) * W + (xx >> 1)];
            c5 = fmaxf(c5, v);
            if (dy >= -1 && dy <= 1 && dx >= -1 && dx <= 1) c3 = fmaxf(c3, v);
        }
    }
    conva[g] = (c5 > 0.f) ? 1.f : 0.f;
    wavem[g] = (c3 > 0.f) ? 1.f : 0.f;
}

// ---------------------------------------------------------------------------
// workspace layout (bytes)
// ---------------------------------------------------------------------------
static constexpr size_t WSTEM = 0;             // 66,769,920 (9*1104*3360*2), both phases
static constexpr size_t WUP1  = 0;             // 46,780,416 (9*576*4512*2)
static constexpr size_t X16   = 46780416ull;   // 7,864,320
static constexpr size_t WUP2  = 54644736ull;   // 11,943,936 (9*288*2304*2) end 66,588,672
static constexpr size_t XB    = 0ull;          // 23,592,960 (over WUP1, dead)
static constexpr size_t X4    = 23592960ull;   // 15,728,640 (over WUP1, dead) end 39,321,600
static constexpr size_t WUP3  = 66769920ull;   // 995,328  (over X32, dead)
static constexpr size_t WV1   = 67765248ull;   // 79,488
static constexpr size_t WV2   = 67844736ull;   // 40,320
static constexpr size_t WV3   = 67885056ull;   // 20,736 end 67,905,792
static constexpr size_t X32   = 66769920ull;   // 11,304,960 end 78,074,880
static constexpr size_t XD0   = 78074880ull;   // 5,652,480  end 83,727,360
static constexpr size_t ZPADO = 83727360ull;   // 16,384 zero page (A/W redirect + X32 tail guard)
static constexpr size_t PF    = 83743744ull;   // 27,131,904 (stem P; up1 P; then XA)
static constexpr size_t XAOF  = 83743744ull;   // 23,592,960 end 107,336,704
static constexpr size_t XD1   = 110859264ull;  // 11,796,480 end 122,655,744
// (stem-Pf tail [110.86M,110.88M) overlaps XD1 head; temporally disjoint:
//  stem Pf dead after stem reduce, XD1 written later by up1 reduce.)
static constexpr size_t X8    = 122655744ull;  // 15,728,640 end 138,384,384
static constexpr size_t F32B  = 138384384ull;
static constexpr size_t O_LL1 = 0, O_H1 = 5120, O_LLB = 20480, O_H2 = 40960;
static constexpr size_t O_LLC = 102400, O_H3 = 184320, O_M1 = 430080;
static constexpr size_t O_UPM1 = 435200, O_CAM1 = 440320, O_WM1 = 460800;
static constexpr size_t O_M2 = 481280, O_UPM2 = 501760, O_CAM2 = 522240;
static constexpr size_t O_WM2 = 604160, O_RED = 686080;

extern "C" void kernel_launch(void* const* d_in, const int* in_sizes, int n_in,
                              void* d_out, int out_size, void* d_ws, size_t ws_size,
                              hipStream_t stream)
{
    const float* x32     = (const float*)d_in[0];
    const float* x16     = (const float*)d_in[1];
    const float* x8      = (const float*)d_in[2];
    const float* x4      = (const float*)d_in[3];
    const float* conv2_w = (const float*)d_in[4];
    const float* conv2_b = (const float*)d_in[5];
    const float* up1_w   = (const float*)d_in[6];
    const float* up1_b   = (const float*)d_in[7];
    const float* w1ll_w  = (const float*)d_in[8];
    const float* w1ll_b  = (const float*)d_in[9];
    const float* w1_w    = (const float*)d_in[10];
    const float* w1_b    = (const float*)d_in[11];
    const float* up2_w   = (const float*)d_in[12];
    const float* up2_b   = (const float*)d_in[13];
    const float* w2_w    = (const float*)d_in[14];
    const float* w2_b    = (const float*)d_in[15];
    const float* up3_w   = (const float*)d_in[16];
    const float* up3_b   = (const float*)d_in[17];
    const float* w3_w    = (const float*)d_in[18];
    const float* w3_b    = (const float*)d_in[19];

    char* ws = (char*)d_ws;
    auto U = [&](size_t off) { return (ushort*)(ws + off); };
    float* Pf  = (float*)(ws + PF);
    float* f32 = (float*)(ws + F32B);
    float* ll1   = f32 + O_LL1;
    float* h1    = f32 + O_H1;
    float* llb   = f32 + O_LLB;
    float* h2    = f32 + O_H2;
    float* llc   = f32 + O_LLC;
    float* h3    = f32 + O_H3;
    float* mask1 = f32 + O_M1;
    float* upm1  = f32 + O_UPM1;
    float* cam1  = f32 + O_CAM1;
    float* wm1   = f32 + O_WM1;
    float* mask2 = f32 + O_M2;
    float* upm2  = f32 + O_UPM2;
    float* cam2  = f32 + O_CAM2;
    float* wm2   = f32 + O_WM2;
    float* wv1   = (float*)(ws + WV1);
    float* wv2   = (float*)(ws + WV2);
    float* wv3   = (float*)(ws + WV3);
    const ushort* zp = U(ZPADO);

    // ---- zero page + XD0 head guard (every launch; XD0 head later rewritten
    //      by stem reduce, read only as X32-overshoot guard by stem conv) ----
    zero_k<<<1, 256, 0, stream>>>(U(ZPADO), U(XD0));

    // ---- stem: 2 IC-phases, split-K 4, RMW partials; 16-col/NOC48 async ----
    repack_x_k<true><<<dim3(5, 69, 4), 256, 0, stream>>>(x32, U(X32), 2208, 320, 4416, 2208);
    repack_w_k<<<1812, 256, 0, stream>>>(conv2_w, U(WSTEM), 1104, 2208, 0, 1104, 1120, 0, 0, 8, 3, 1104, 3360);
    conv_async_k<0, 4, 1, 1, 1, 3, 10, 32, 1104, 3360, 1120, 8, 3, 4416, 2208, 0, 1, 4, false, false>
        <<<dim3(6, 23, 16), 256, 0, stream>>>(U(X32), nullptr, U(WSTEM), nullptr,
            nullptr, nullptr, nullptr, zp, nullptr, Pf, 1104);
    repack_w_k<<<1812, 256, 0, stream>>>(conv2_w, U(WSTEM), 1104, 2208, 1104, 1104, 1120, 0, 0, 8, 3, 1104, 3360);
    conv_async_k<0, 4, 1, 1, 1, 3, 10, 32, 1104, 3360, 1120, 8, 3, 4416, 2208, 1104, 1, 4, false, true>
        <<<dim3(6, 23, 16), 256, 0, stream>>>(U(X32), nullptr, U(WSTEM), nullptr,
            nullptr, nullptr, nullptr, zp, nullptr, Pf, 1104);
    reduce_k<4, 12, 10, 32, 1104, false><<<1380, 256, 0, stream>>>(Pf, conv2_b, U(XD0), 1104);
    // ---- phase B repacks (WSTEM/X32 regions now dead) ----
    repack_w_k<<<1269, 256, 0, stream>>>(up1_w, U(WUP1), 552, 1488, 0, 1104, 1120, 1104, 384, 384, 3, 576, 4512);
    repack_x_k<true><<<dim3(20, 12, 4), 256, 0, stream>>>(x16, U(X16), 384, 1280, 768, 384);
    repack_w_k<<<324, 256, 0, stream>>>(up2_w, U(WUP2), 276, 744, 0, 552, 576, 552, 192, 192, 3, 288, 2304);
    repack_w_k<<<27, 256, 0, stream>>>(up3_w, U(WUP3), 138, 372, 0, 276, 288, 276, 96, 96, 1, 144, 384);
    repack_x_k<true><<<dim3(80, 6, 4), 256, 0, stream>>>(x8, U(X8), 192, 5120, 384, 192);
    repack_wv_k<<<20, 256, 0, stream>>>(w1_w, w1ll_w, wv1, 552, 552);
    repack_wv_k<<<10, 256, 0, stream>>>(w2_w, nullptr, wv2, 276, 280);
    repack_wv_k<<<6, 256, 0, stream>>>(w3_w, nullptr, wv3, 138, 144);
    // ---- up1 (split-K 2, NOC32 async) ----
    conv_async_k<1, 2, 2, 2, 1, 2, 20, 64, 576, 4512, 1120, 384, 3, 2208, 1104, 0, 768, 2, false, false>
        <<<dim3(10, 18, 8), 256, 0, stream>>>(U(XD0), U(X16), U(WUP1), nullptr,
            nullptr, nullptr, nullptr, zp, nullptr, Pf, 552);
    reduce_k<2, 20, 20, 64, 576, true><<<2880, 256, 0, stream>>>(Pf, up1_b, U(XD1), 552);
    repack_x_k<false><<<dim3(320, 3, 4), 256, 0, stream>>>(x4, U(X4), 96, 20480, 96, 0);
    // ---- wave1 + level-1 masks ----
    wave_cl_k<69, 1152, 576, 20, 64, false, true><<<1280, 256, 0, stream>>>(
        U(XD1), wv1, w1_b, w1ll_b, nullptr, 4.f, h1, ll1);
    idwt_k<20, 64><<<20, 256, 0, stream>>>(ll1, h1, llb);
    minmax_k<<<1, 256, 0, stream>>>(llb, 20480, f32 + O_RED);
    mask_k<20, 64><<<20, 256, 0, stream>>>(h1, f32 + O_RED, mask1);
    dilate_k<20, 64, 2><<<20, 256, 0, stream>>>(mask1, upm1);
    masksfull_k<20, 64><<<80, 256, 0, stream>>>(mask1, cam1, wm1);
    // ---- up2 (NOC32 async, masked) ----
    conv_async_k<2, 2, 2, 2, 1, 2, 40, 128, 288, 2304, 576, 192, 3, 1152, 576, 0, 384, 1, true, false>
        <<<dim3(40, 9, 4), 256, 0, stream>>>(U(XD1), U(X8), U(WUP2), up2_b,
            upm1, cam1, wm1, zp, U(XAOF), nullptr, 276);
    // ---- wave2 + level-0 masks ----
    wave_cl_k<35, 576, 288, 40, 128, false, false><<<5120, 256, 0, stream>>>(
        U(XAOF), wv2, w2_b, nullptr, mask1, 2.f, h2, nullptr);
    idwt_k<40, 128><<<80, 256, 0, stream>>>(llb, h2, llc);
    minmax_k<<<1, 256, 0, stream>>>(llc, 81920, f32 + O_RED + 1);
    mask_k<40, 128><<<80, 256, 0, stream>>>(h2, f32 + O_RED + 1, mask2);
    dilate_k<40, 128, 2><<<80, 256, 0, stream>>>(mask2, upm2);
    masksfull_k<40, 128><<<320, 256, 0, stream>>>(mask2, cam2, wm2);
    // ---- up3 (single bf16, NOC16 async, masked) ----
    conv_async_k<2, 2, 2, 2, 1, 1, 80, 256, 144, 384, 288, 96, 1, 576, 288, 0, 96, 1, false, false>
        <<<dim3(160, 9, 4), 256, 0, stream>>>(U(XAOF), U(X4), U(WUP3), up3_b,
            upm2, cam2, wm2, zp, U(XB), nullptr, 138);
    // ---- wave3 + final idwt ----
    wave_cl_k<18, 144, 0, 80, 256, true, false><<<20480, 256, 0, stream>>>(
        U(XB), wv3, w3_b, nullptr, mask2, 1.f, h3, nullptr);
    idwt_k<80, 256><<<320, 256, 0, stream>>>(llc, h3, (float*)d_out);
}

// Round 4
// 2362.170 us; speedup vs baseline: 1.1170x; 1.1170x over previous
//
#include <hip/hip_runtime.h>
#include <hip/hip_bf16.h>
#include <stdint.h>

// ---------------------------------------------------------------------------
// SparseDecoderWave — MFMA bf16 implicit-GEMM, 3-segment K-stacked split.
// K layout per conv: [A_hi | A_lo | A_hi] x [W_hi | W_hi | W_lo]  (SEG=3)
//   => ah*wh + al*wh + ah*wl  (full double-bf16 cross terms, err ~2^-16).
// up3 is single-bf16 (SEG=1).
// Staging: T3 2-phase async — double-buffered LDS, global_load_lds (16B),
//   one barrier per k-chunk. XOR slot swizzle applied on the GLOBAL source
//   permutation (linear LDS dest); reads use swizzled addressing (0 conflicts).
// Masked (MODE 2) / pad lanes redirect src address to a 16KB zero page.
// R4: chunked XCD swizzle, oc-tile slowest — each XCD's L2 owns ~GY/8
//   oc-tiles' weight stream (kills the 8x cross-XCD weight re-fetch:
//   measured 1.05 GB FETCH on stem = 16x weight footprint).
// ---------------------------------------------------------------------------

typedef float f32x4 __attribute__((ext_vector_type(4)));
typedef short s16x8 __attribute__((ext_vector_type(8)));

typedef const __attribute__((address_space(1))) void* gas_ptr;
typedef __attribute__((address_space(3))) void* las_ptr;

__device__ __forceinline__ void gl_lds16(const void* g, void* l) {
    __builtin_amdgcn_global_load_lds((gas_ptr)g, (las_ptr)l, 16, 0, 0);
}

__device__ __forceinline__ ushort f2bf(float f) {
    uint32_t u = __float_as_uint(f);
    u += 0x7FFFu + ((u >> 16) & 1u);
    return (ushort)(u >> 16);
}
__device__ __forceinline__ float bf2f(ushort h) {
    return __uint_as_float(((uint32_t)h) << 16);
}

// ---- zero page + XD0 head guard init (idempotent, runs each launch) ----
__global__ __launch_bounds__(256)
void zero_k(ushort* __restrict__ zp, ushort* __restrict__ xd0head)
{
    const int t = threadIdx.x;
    const uint4 z = {0, 0, 0, 0};
    for (int i = t; i < 1024; i += 256) *(uint4*)(zp + i * 8) = z;  // 16 KB
    if (t < 16) *(uint4*)(xd0head + t * 8) = z;                     // 256 B
}

// ---- weight repack: w[oc][ct][3][3] fp32 -> W'[t][OCP][KT] bf16 ----
__global__ __launch_bounds__(256)
void repack_w_k(const float* __restrict__ w, ushort* __restrict__ out,
                int OC, int CT, int ICOFF, int CAR, int CAP, int CAT,
                int CBR, int CBP, int SEG, int OCP, int KT)
{
    const int KG = KT / 8;
    const int u = blockIdx.x * 256 + threadIdx.x;
    if (u >= OCP * KG) return;
    const int oc = u / KG, kg = u - oc * KG;
    const int k0 = kg * 8;
    int ic, lo; bool ok;
    if (k0 < SEG * CAP) {
        const int seg = k0 / CAP, c = k0 - seg * CAP;
        lo = (seg == 2); ic = ICOFF + c; ok = (c < CAR);
    } else {
        const int kb = k0 - SEG * CAP;
        const int seg = kb / CBP, c = kb - seg * CBP;
        lo = (seg == 2); ic = CAT + c; ok = (c < CBR);
    }
    ok = ok && (oc < OC);
    for (int t = 0; t < 9; ++t) {
        ushort q[8];
#pragma unroll
        for (int j = 0; j < 8; ++j) q[j] = 0;
        if (ok) {
#pragma unroll
            for (int j = 0; j < 8; ++j) {
                const float v = w[((size_t)oc * CT + ic + j) * 9 + t];
                const ushort h = f2bf(v);
                q[j] = lo ? f2bf(v - bf2f(h)) : h;
            }
        }
        *(uint4*)(out + ((size_t)t * OCP + oc) * KT + k0) = *(uint4*)q;
    }
}

// ---- input repack: [b][c][p] fp32 -> [b][p][OST] bf16 hi(+lo at LOOFF) ----
template<bool SPLIT>
__global__ __launch_bounds__(256)
void repack_x_k(const float* __restrict__ in, ushort* __restrict__ out,
                int C, int HW, int OST, int LOOFF)
{
    __shared__ float tile[32][65];
    const int b = blockIdx.z, c0 = blockIdx.y * 32, p0 = blockIdx.x * 64;
    for (int e = threadIdx.x; e < 2048; e += 256) {
        const int cl = e >> 6, pl = e & 63;
        tile[cl][pl] = in[((size_t)b * C + c0 + cl) * HW + p0 + pl];
    }
    __syncthreads();
    const int pl = threadIdx.x >> 2, cg = (threadIdx.x & 3) * 8;
    ushort hv[8], lv[8];
#pragma unroll
    for (int j = 0; j < 8; ++j) {
        const float v = tile[cg + j][pl];
        const ushort h = f2bf(v);
        hv[j] = h;
        lv[j] = f2bf(v - bf2f(h));
    }
    const size_t o = ((size_t)b * HW + p0 + pl) * OST + c0 + cg;
    *(uint4*)(out + o) = *(uint4*)hv;
    if constexpr (SPLIT) *(uint4*)(out + LOOFF + o) = *(uint4*)lv;
}

// ---- async MFMA conv3x3: double-buffered LDS, global_load_lds staging ----
// MODE 0: edge pad (stem); MODE 1: reflect, A up2x (up1);
// MODE 2: reflect, A up2x, mask-redirected staging + leaky*wvm epilogue.
template<int MODE, int WR, int WC, int WROWS, int WCOLF, int NOCF,
         int H, int W, int OCP, int KT, int CAP, int CBP, int SEG,
         int ASTR, int APLSTR, int AOFF, int BSTR, int KS,
         bool SOUT, bool ACCIN>
__global__ __launch_bounds__(256, 2)
void conv_async_k(const ushort* __restrict__ xA, const ushort* __restrict__ xB,
                  const ushort* __restrict__ wgt, const float* __restrict__ bias,
                  const float* __restrict__ upm, const float* __restrict__ cam,
                  const float* __restrict__ wvm, const ushort* __restrict__ zpad,
                  ushort* __restrict__ outb, float* __restrict__ outp, int OC)
{
    constexpr int BROWS = WR * WROWS;
    constexpr int BCOLS = WC * WCOLF * 16;
    constexpr int NOC = NOCF * 16;
    constexpr int PH = BROWS + 2, PW = BCOLS + 2;
    constexpr int NPX = PH * PW;
    constexpr int NAU = NPX * 4;                    // A 16B slots
    constexpr int ASL = ((NAU + 63) / 64) * 64;     // wave-padded
    constexpr int NWU = 9 * NOC * 4;                // W 16B slots (mult of 64)
    constexpr int NSA = (ASL + 255) / 256;
    constexpr int NSW = (NWU + 255) / 256;
    constexpr int PERBUF = (ASL + NWU) * 8;         // ushorts per buffer
    constexpr int NCH = KT / 32;
    constexpr int XT = W / BCOLS;
    constexpr int HP = ((H + BROWS - 1) / BROWS) * BROWS;
    constexpr int HA = (MODE == 0) ? H : H / 2;
    constexpr int WA = (MODE == 0) ? W : W / 2;
    constexpr bool HASB = (SEG * CAP < KT);

    __shared__ __align__(16) ushort lds[2 * PERBUF];

    const int tid = threadIdx.x;

    // ---- chunked XCD swizzle (tot % 8 == 0 for all launches): oc slowest
    //      so each XCD's private L2 owns a contiguous oc-tile weight range.
    const int GX = gridDim.x, GY = gridDim.y, GZ = gridDim.z;
    const int L = blockIdx.x + GX * (blockIdx.y + GY * blockIdx.z);
    const int cpx = (GX * GY * GZ) >> 3;
    const int wsw = (L & 7) * cpx + (L >> 3);
    const int bky = wsw / (GX * GZ);
    const int rem = wsw - bky * (GX * GZ);
    const int bkz = rem / GX;
    const int bkx = rem - bkz * GX;

    const int b = bkz / KS, sid = bkz % KS;
    const int oc0 = bky * NOC;
    const int y0 = (bkx / XT) * BROWS;
    const int x0 = (bkx % XT) * BCOLS;
    const int lane = tid & 63, wv = tid >> 6;
    const int wr = wv / WC, wc = wv % WC;
    const int lq = lane >> 4, ln = lane & 15;
    const int wcb = wc * (WCOLF * 16);
    const int c0 = (sid * NCH) / KS, c1 = ((sid + 1) * NCH) / KS;
    const int wbv = wv * 512;                       // wave slot base (ushorts)

    // ---- A staging geometry (k-independent, source-permuted by swizzle) ----
    const ushort* pAp[NSA]; const ushort* pBp[NSA]; int aKO[NSA];
    for (int s = 0; s < NSA; ++s) {
        const int u = tid + s * 256;
        const int pp = u >> 2, sl = u & 3;
        aKO[s] = (sl ^ ((pp >> 1) & 3)) * 8;        // pre-swizzled k-group
        const bool val = pp < NPX;
        const int ppc = val ? pp : 0;
        const int py = ppc / PW, px = ppc - py * PW;
        int y = y0 + py - 1, x = x0 + px - 1;
        if (MODE == 0) { y = min(max(y, 0), H - 1); x = min(max(x, 0), W - 1); }
        else { y = (y < 0) ? -y : ((y >= H) ? 2 * H - 2 - y : y);
               x = (x < 0) ? -x : ((x >= W) ? 2 * W - 2 - x : x); }
        const int ya = (MODE == 0) ? y : (y >> 1);
        const int xa = (MODE == 0) ? x : (x >> 1);
        bool okA = val, okB = val;
        if (MODE == 2) {
            const float cm = cam[((size_t)b * H + y) * W + x];
            const float um = upm[((size_t)b * HA + ya) * WA + xa];
            okA = okA && (um * cm != 0.f);
            okB = okB && (cm != 0.f);
        }
        pAp[s] = okA ? xA + (size_t)((b * HA + ya) * WA + xa) * ASTR : zpad;
        if constexpr (HASB)
            pBp[s] = okB ? xB + (size_t)((b * H + y) * W + x) * BSTR : zpad;
        else
            pBp[s] = zpad;
    }
    // ---- W staging geometry ----
    const ushort* pWp[NSW];
    for (int s = 0; s < NSW; ++s) {
        const int u = tid + s * 256;
        const int wrow = u >> 2, sl = u & 3;
        const int kg = sl ^ ((wrow >> 1) & 3);      // pre-swizzled k-group
        const int t = wrow / NOC, ocl = wrow - t * NOC;  // true modulo (NOC=48 ok)
        pWp[s] = (u < NWU) ?
            wgt + (size_t)(t * OCP + oc0 + ocl) * KT + kg * 8 : zpad;
    }

    auto stage = [&](int buf, int kc) {
        ushort* ab = lds + buf * PERBUF;
        ushort* wb = ab + ASL * 8;
        const int ko = kc * 32;
#pragma unroll
        for (int s = 0; s < NSA; ++s) {
            if (s * 256 + wv * 64 < NAU) {          // wave-uniform skip
                const int k = ko + aKO[s];
                const ushort* g;
                if (!HASB || k < SEG * CAP) {
                    int ka = (SEG == 3 && k >= 2 * CAP) ? k - 2 * CAP : k;
                    const int pl = (ka >= CAP) ? 1 : 0;
                    g = pAp[s] + pl * APLSTR + AOFF + (ka - pl * CAP);
                } else {
                    int kb = k - SEG * CAP;
                    if (SEG == 3 && kb >= 2 * CBP) kb -= 2 * CBP;
                    g = pBp[s] + kb;
                }
                gl_lds16(g, ab + s * 2048 + wbv);
            }
        }
#pragma unroll
        for (int s = 0; s < NSW; ++s)
            if (s * 256 + wv * 64 < NWU)            // wave-uniform skip
                gl_lds16(pWp[s] + ko, wb + s * 2048 + wbv);
    };

    f32x4 acc[WROWS][WCOLF][NOCF];
#pragma unroll
    for (int i = 0; i < WROWS; ++i)
#pragma unroll
        for (int c = 0; c < WCOLF; ++c)
#pragma unroll
            for (int n = 0; n < NOCF; ++n) acc[i][c][n] = {0.f, 0.f, 0.f, 0.f};

    if (ACCIN) {
#pragma unroll
        for (int ri = 0; ri < WROWS; ++ri) {
            const float* Pr = outp +
                ((((size_t)sid * 4 + b) * HP + y0 + wr * WROWS + ri) * W + x0 + wcb) * OCP;
#pragma unroll
            for (int cf = 0; cf < WCOLF; ++cf)
#pragma unroll
                for (int n2 = 0; n2 < NOCF; ++n2)
#pragma unroll
                    for (int r = 0; r < 4; ++r)
                        acc[ri][cf][n2][r] =
                            Pr[(size_t)(cf * 16 + lq * 4 + r) * OCP + oc0 + n2 * 16 + ln];
        }
    }

    stage(0, c0);
    __syncthreads();                                 // vmcnt drain: buf0 ready
    int cur = 0;
    for (int kc = c0; kc < c1; ++kc) {
        if (kc + 1 < c1) stage(cur ^ 1, kc + 1);     // async into other buffer
        const ushort* at = lds + cur * PERBUF;
        const ushort* wt = at + ASL * 8;
        // ---- preload A fragments (swizzled reads, conflict-free) ----
        s16x8 afr[WROWS + 2][WCOLF][3];
#pragma unroll
        for (int ar = 0; ar < WROWS + 2; ++ar)
#pragma unroll
            for (int cf = 0; cf < WCOLF; ++cf)
#pragma unroll
                for (int dx = 0; dx < 3; ++dx) {
                    const int p = (wr * WROWS + ar) * PW + wcb + cf * 16 + ln + dx;
                    afr[ar][cf][dx] = *(const s16x8*)
                        &at[p * 32 + ((lq ^ ((p >> 1) & 3)) * 8)];
                }
        // ---- 9 taps ----
#pragma unroll
        for (int t = 0; t < 9; ++t) {
            const int dy = t / 3, dx = t - dy * 3;
#pragma unroll
            for (int n2 = 0; n2 < NOCF; ++n2) {
                const int wrow = t * NOC + n2 * 16 + ln;
                const s16x8 bw = *(const s16x8*)
                    &wt[wrow * 32 + ((lq ^ ((wrow >> 1) & 3)) * 8)];
#pragma unroll
                for (int ri = 0; ri < WROWS; ++ri)
#pragma unroll
                    for (int cf = 0; cf < WCOLF; ++cf)
                        acc[ri][cf][n2] = __builtin_amdgcn_mfma_f32_16x16x32_bf16(
                            afr[ri + dy][cf][dx], bw, acc[ri][cf][n2], 0, 0, 0);
            }
        }
        __syncthreads();   // drains lgkm (reads done) + vmcnt (next buf staged)
        cur ^= 1;
    }

    // ---- epilogue ----
    if (KS > 1) {
#pragma unroll
        for (int ri = 0; ri < WROWS; ++ri) {
            float* Pr = outp +
                ((((size_t)sid * 4 + b) * HP + y0 + wr * WROWS + ri) * W + x0 + wcb) * OCP;
#pragma unroll
            for (int cf = 0; cf < WCOLF; ++cf)
#pragma unroll
                for (int n2 = 0; n2 < NOCF; ++n2)
#pragma unroll
                    for (int r = 0; r < 4; ++r)
                        Pr[(size_t)(cf * 16 + lq * 4 + r) * OCP + oc0 + n2 * 16 + ln] =
                            acc[ri][cf][n2][r];
        }
    } else {
        constexpr int OST = SOUT ? 2 * OCP : OCP;
#pragma unroll
        for (int ri = 0; ri < WROWS; ++ri) {
            const int y = y0 + wr * WROWS + ri;
#pragma unroll
            for (int cf = 0; cf < WCOLF; ++cf)
#pragma unroll
                for (int n2 = 0; n2 < NOCF; ++n2) {
                    const int oc = oc0 + n2 * 16 + ln;
                    const float bv = (oc < OC) ? bias[oc] : 0.f;
#pragma unroll
                    for (int r = 0; r < 4; ++r) {
                        const int x = x0 + wcb + cf * 16 + lq * 4 + r;
                        float v = acc[ri][cf][n2][r] + bv;
                        v = v > 0.f ? v : 0.2f * v;
                        v *= wvm[((size_t)b * H + y) * W + x];
                        if (oc >= OC) v = 0.f;
                        const size_t o = (((size_t)b * H + y) * W + x) * OST + oc;
                        const ushort h = f2bf(v);
                        outb[o] = h;
                        if constexpr (SOUT) outb[o + OCP] = f2bf(v - bf2f(h));
                    }
                }
        }
    }
}

// ---- split-K reduce: sum fp32 partials, bias(+leaky), bf16 hi/lo store ----
template<int KS, int HP, int H, int W, int OCP, bool ACT>
__global__ __launch_bounds__(256)
void reduce_k(const float* __restrict__ P, const float* __restrict__ bias,
              ushort* __restrict__ out, int OC)
{
    constexpr int OG = OCP / 4;
    const int u = blockIdx.x * 256 + threadIdx.x;
    if (u >= 4 * H * W * OG) return;
    const int og = u % OG;
    const int px = u / OG;
    const int x = px % W, y = (px / W) % H, b = px / (W * H);
    float4 s = {0.f, 0.f, 0.f, 0.f};
    for (int sid = 0; sid < KS; ++sid) {
        const float4 v = *(const float4*)
            (P + ((((size_t)sid * 4 + b) * HP + y) * W + x) * OCP + og * 4);
        s.x += v.x; s.y += v.y; s.z += v.z; s.w += v.w;
    }
    const int oc = og * 4;
    const float vv[4] = {s.x, s.y, s.z, s.w};
    ushort hi[4], lo[4];
#pragma unroll
    for (int j = 0; j < 4; ++j) {
        float v = (oc + j < OC) ? vv[j] + bias[oc + j] : 0.f;
        if (ACT) v = v > 0.f ? v : 0.2f * v;
        const ushort h = f2bf(v);
        hi[j] = h;
        lo[j] = f2bf(v - bf2f(h));
    }
    const size_t o = (size_t)px * 2 * OCP + oc;
    *(uint2*)(out + o) = *(uint2*)hi;
    *(uint2*)(out + o + OCP) = *(uint2*)lo;
}

// ---- wave weight repack: wh[3][C][9](+wll[C][9]) -> Wv[t][CP][4] fp32 ----
__global__ __launch_bounds__(256)
void repack_wv_k(const float* __restrict__ wh, const float* __restrict__ wll,
                 float* __restrict__ out, int C, int CP)
{
    const int u = blockIdx.x * 256 + threadIdx.x;
    if (u >= 9 * CP) return;
    const int t = u / CP, ic = u - t * CP;
    float4 v = {0.f, 0.f, 0.f, 0.f};
    if (ic < C) {
        v.x = wh[((size_t)0 * C + ic) * 9 + t];
        v.y = wh[((size_t)1 * C + ic) * 9 + t];
        v.z = wh[((size_t)2 * C + ic) * 9 + t];
        if (wll) v.w = wll[(size_t)ic * 9 + t];
    }
    *(float4*)(out + (size_t)u * 4) = v;
}

// ---- wave convs from channel-last bf16 (hi at +0, lo at +LOOFF) ----
template<int G, int CSTR, int LOOFF, int H, int W, bool SIN, bool HAS_LL>
__global__ __launch_bounds__(256)
void wave_cl_k(const ushort* __restrict__ xq, const float* __restrict__ wv,
               const float* __restrict__ bh, const float* __restrict__ bll,
               const float* __restrict__ mhalf, float scale,
               float* __restrict__ outh, float* __restrict__ outll)
{
    const int lane = threadIdx.x & 63;
    const int pix = blockIdx.x * 4 + (threadIdx.x >> 6);
    const int x = pix % W, y = (pix / W) % H, b = pix / (W * H);
    float a0 = 0.f, a1 = 0.f, a2 = 0.f, a3 = 0.f;
    for (int it = lane; it < 9 * G; it += 64) {
        const int t = it / G, g = it - t * G;
        const int dy = t / 3 - 1, dx = t % 3 - 1;
        const int yy = y + dy, xx = x + dx;
        const int yc = min(max(yy, 0), H - 1), xc = min(max(xx, 0), W - 1);
        const bool inr = (yy >= 0) && (yy < H) && (xx >= 0) && (xx < W);
        const size_t base = (((size_t)b * H + yc) * W + xc) * CSTR + g * 8;
        const uint4 hv = *(const uint4*)(xq + base);
        uint4 lv = {0, 0, 0, 0};
        if constexpr (!SIN) lv = *(const uint4*)(xq + base + LOOFF);
        const float4* wp = (const float4*)(wv + ((size_t)t * (G * 8) + g * 8) * 4);
        const uint* hw = (const uint*)&hv;
        const uint* lw = (const uint*)&lv;
#pragma unroll
        for (int j = 0; j < 8; ++j) {
            const uint wd = hw[j >> 1];
            float xf = (j & 1) ? __uint_as_float(wd & 0xFFFF0000u)
                               : __uint_as_float(wd << 16);
            if constexpr (!SIN) {
                const uint wl = lw[j >> 1];
                xf += (j & 1) ? __uint_as_float(wl & 0xFFFF0000u)
                              : __uint_as_float(wl << 16);
            }
            const float xz = inr ? xf : 0.f;
            const float4 w4 = wp[j];
            a0 = fmaf(w4.x, xz, a0);
            a1 = fmaf(w4.y, xz, a1);
            a2 = fmaf(w4.z, xz, a2);
            if constexpr (HAS_LL) a3 = fmaf(w4.w, xf, a3);
        }
    }
#pragma unroll
    for (int o = 1; o < 64; o <<= 1) {
        a0 += __shfl_xor(a0, o);
        a1 += __shfl_xor(a1, o);
        a2 += __shfl_xor(a2, o);
        if constexpr (HAS_LL) a3 += __shfl_xor(a3, o);
    }
    if (lane == 0) {
        float wm = 1.f;
        if (mhalf) wm = mhalf[((size_t)b * (H / 2) + (y >> 1)) * (W / 2) + (x >> 1)];
        const size_t hb = (size_t)b * 3 * H * W + (size_t)y * W + x;
        outh[hb]             = (a0 + bh[0]) * scale * wm;
        outh[hb + H * W]     = (a1 + bh[1]) * scale * wm;
        outh[hb + 2 * H * W] = (a2 + bh[2]) * scale * wm;
        if constexpr (HAS_LL) outll[((size_t)b * H + y) * W + x] = (a3 + bll[0]) * 8.f;
    }
}

// ---- inverse Haar DWT ----
template<int H, int W>
__global__ __launch_bounds__(256)
void idwt_k(const float* __restrict__ ll, const float* __restrict__ h,
            float* __restrict__ out)
{
    const int g = blockIdx.x * 256 + threadIdx.x;
    if (g >= 4 * H * W) return;
    const int x = g % W, y = (g / W) % H, b = g / (W * H);
    const float l  = ll[g];
    const float lh = h[((size_t)(b * 3 + 0) * H + y) * W + x];
    const float hl = h[((size_t)(b * 3 + 1) * H + y) * W + x];
    const float hh = h[((size_t)(b * 3 + 2) * H + y) * W + x];
    const float x00 = (l + lh + hl + hh) * 0.5f;
    const float x01 = (l - lh + hl - hh) * 0.5f;
    const float x10 = (l + lh - hl - hh) * 0.5f;
    const float x11 = (l - lh - hl + hh) * 0.5f;
    float* ob = out + (size_t)b * (2 * H) * (2 * W);
    ob[(size_t)(2 * y) * (2 * W) + 2 * x]         = x00;
    ob[(size_t)(2 * y) * (2 * W) + 2 * x + 1]     = x01;
    ob[(size_t)(2 * y + 1) * (2 * W) + 2 * x]     = x10;
    ob[(size_t)(2 * y + 1) * (2 * W) + 2 * x + 1] = x11;
}

__global__ __launch_bounds__(256)
void minmax_k(const float* __restrict__ p, int n, float* __restrict__ thr)
{
    __shared__ float smax[256], smin[256];
    float mx = -1e30f, mn = 1e30f;
    for (int i = threadIdx.x; i < n; i += 256) {
        const float v = p[i];
        mx = fmaxf(mx, v);
        mn = fminf(mn, v);
    }
    smax[threadIdx.x] = mx;
    smin[threadIdx.x] = mn;
    __syncthreads();
    for (int s = 128; s > 0; s >>= 1) {
        if (threadIdx.x < s) {
            smax[threadIdx.x] = fmaxf(smax[threadIdx.x], smax[threadIdx.x + s]);
            smin[threadIdx.x] = fminf(smin[threadIdx.x], smin[threadIdx.x + s]);
        }
        __syncthreads();
    }
    if (threadIdx.x == 0) *thr = (smax[0] - smin[0]) * 0.1f;
}

template<int H, int W>
__global__ __launch_bounds__(256)
void mask_k(const float* __restrict__ h, const float* __restrict__ thr,
            float* __restrict__ mask)
{
    const int g = blockIdx.x * 256 + threadIdx.x;
    if (g >= 4 * H * W) return;
    const int x = g % W, y = (g / W) % H, b = g / (W * H);
    const float t  = *thr;
    const float v0 = fabsf(h[((size_t)(b * 3 + 0) * H + y) * W + x]);
    const float v1 = fabsf(h[((size_t)(b * 3 + 1) * H + y) * W + x]);
    const float v2 = fabsf(h[((size_t)(b * 3 + 2) * H + y) * W + x]);
    mask[g] = (fmaxf(v0, fmaxf(v1, v2)) > t) ? 1.f : 0.f;
}

template<int H, int W, int R>
__global__ __launch_bounds__(256)
void dilate_k(const float* __restrict__ m, float* __restrict__ o)
{
    const int g = blockIdx.x * 256 + threadIdx.x;
    if (g >= 4 * H * W) return;
    const int x = g % W, y = (g / W) % H, b = g / (W * H);
    float v = 0.f;
    for (int dy = -R; dy <= R; ++dy) {
        const int yy = y + dy;
        if (yy < 0 || yy >= H) continue;
        for (int dx = -R; dx <= R; ++dx) {
            const int xx = x + dx;
            if (xx < 0 || xx >= W) continue;
            v = fmaxf(v, m[((size_t)b * H + yy) * W + xx]);
        }
    }
    o[g] = (v > 0.f) ? 1.f : 0.f;
}

template<int H, int W>
__global__ __launch_bounds__(256)
void masksfull_k(const float* __restrict__ m, float* __restrict__ conva,
                 float* __restrict__ wavem)
{
    const int g = blockIdx.x * 256 + threadIdx.x;
    constexpr int H2 = 2 * H, W2 = 2 * W;
    if (g >= 4 * H2 * W2) return;
    const int x = g % W2, y = (g / W2) % H2, b = g / (W2 * H2);
    float c5 = 0.f, c3 = 0.f;
    for (int dy = -2; dy <= 2; ++dy) {
        const int yy = y + dy;
        if (yy < 0 || yy >= H2) continue;
        const int my = yy >> 1;
        for (int dx = -2; dx <= 2; ++dx) {
            const int xx = x + dx;
            if (xx < 0 || xx >= W2) continue;
            const float v = m[((size_t)b * H + my) * W + (xx >> 1)];
            c5 = fmaxf(c5, v);
            if (dy >= -1 && dy <= 1 && dx >= -1 && dx <= 1) c3 = fmaxf(c3, v);
        }
    }
    conva[g] = (c5 > 0.f) ? 1.f : 0.f;
    wavem[g] = (c3 > 0.f) ? 1.f : 0.f;
}

// ---------------------------------------------------------------------------
// workspace layout (bytes)
// ---------------------------------------------------------------------------
static constexpr size_t WSTEM = 0;             // 66,769,920 (9*1104*3360*2), both phases
static constexpr size_t WUP1  = 0;             // 46,780,416 (9*576*4512*2)
static constexpr size_t X16   = 46780416ull;   // 7,864,320
static constexpr size_t WUP2  = 54644736ull;   // 11,943,936 (9*288*2304*2) end 66,588,672
static constexpr size_t XB    = 0ull;          // 23,592,960 (over WUP1, dead)
static constexpr size_t X4    = 23592960ull;   // 15,728,640 (over WUP1, dead) end 39,321,600
static constexpr size_t WUP3  = 66769920ull;   // 995,328  (over X32, dead)
static constexpr size_t WV1   = 67765248ull;   // 79,488
static constexpr size_t WV2   = 67844736ull;   // 40,320
static constexpr size_t WV3   = 67885056ull;   // 20,736 end 67,905,792
static constexpr size_t X32   = 66769920ull;   // 11,304,960 end 78,074,880
static constexpr size_t XD0   = 78074880ull;   // 5,652,480  end 83,727,360
static constexpr size_t ZPADO = 83727360ull;   // 16,384 zero page (A/W redirect + X32 tail guard)
static constexpr size_t PF    = 83743744ull;   // 27,131,904 (stem P; up1 P; then XA)
static constexpr size_t XAOF  = 83743744ull;   // 23,592,960 end 107,336,704
static constexpr size_t XD1   = 110859264ull;  // 11,796,480 end 122,655,744
// (stem-Pf tail [110.86M,110.88M) overlaps XD1 head; temporally disjoint:
//  stem Pf dead after stem reduce, XD1 written later by up1 reduce.)
static constexpr size_t X8    = 122655744ull;  // 15,728,640 end 138,384,384
static constexpr size_t F32B  = 138384384ull;
static constexpr size_t O_LL1 = 0, O_H1 = 5120, O_LLB = 20480, O_H2 = 40960;
static constexpr size_t O_LLC = 102400, O_H3 = 184320, O_M1 = 430080;
static constexpr size_t O_UPM1 = 435200, O_CAM1 = 440320, O_WM1 = 460800;
static constexpr size_t O_M2 = 481280, O_UPM2 = 501760, O_CAM2 = 522240;
static constexpr size_t O_WM2 = 604160, O_RED = 686080;

extern "C" void kernel_launch(void* const* d_in, const int* in_sizes, int n_in,
                              void* d_out, int out_size, void* d_ws, size_t ws_size,
                              hipStream_t stream)
{
    const float* x32     = (const float*)d_in[0];
    const float* x16     = (const float*)d_in[1];
    const float* x8      = (const float*)d_in[2];
    const float* x4      = (const float*)d_in[3];
    const float* conv2_w = (const float*)d_in[4];
    const float* conv2_b = (const float*)d_in[5];
    const float* up1_w   = (const float*)d_in[6];
    const float* up1_b   = (const float*)d_in[7];
    const float* w1ll_w  = (const float*)d_in[8];
    const float* w1ll_b  = (const float*)d_in[9];
    const float* w1_w    = (const float*)d_in[10];
    const float* w1_b    = (const float*)d_in[11];
    const float* up2_w   = (const float*)d_in[12];
    const float* up2_b   = (const float*)d_in[13];
    const float* w2_w    = (const float*)d_in[14];
    const float* w2_b    = (const float*)d_in[15];
    const float* up3_w   = (const float*)d_in[16];
    const float* up3_b   = (const float*)d_in[17];
    const float* w3_w    = (const float*)d_in[18];
    const float* w3_b    = (const float*)d_in[19];

    char* ws = (char*)d_ws;
    auto U = [&](size_t off) { return (ushort*)(ws + off); };
    float* Pf  = (float*)(ws + PF);
    float* f32 = (float*)(ws + F32B);
    float* ll1   = f32 + O_LL1;
    float* h1    = f32 + O_H1;
    float* llb   = f32 + O_LLB;
    float* h2    = f32 + O_H2;
    float* llc   = f32 + O_LLC;
    float* h3    = f32 + O_H3;
    float* mask1 = f32 + O_M1;
    float* upm1  = f32 + O_UPM1;
    float* cam1  = f32 + O_CAM1;
    float* wm1   = f32 + O_WM1;
    float* mask2 = f32 + O_M2;
    float* upm2  = f32 + O_UPM2;
    float* cam2  = f32 + O_CAM2;
    float* wm2   = f32 + O_WM2;
    float* wv1   = (float*)(ws + WV1);
    float* wv2   = (float*)(ws + WV2);
    float* wv3   = (float*)(ws + WV3);
    const ushort* zp = U(ZPADO);

    // ---- zero page + XD0 head guard (every launch; XD0 head later rewritten
    //      by stem reduce, read only as X32-overshoot guard by stem conv) ----
    zero_k<<<1, 256, 0, stream>>>(U(ZPADO), U(XD0));

    // ---- stem: 2 IC-phases, split-K 4, RMW partials; 16-col/NOC48 async ----
    repack_x_k<true><<<dim3(5, 69, 4), 256, 0, stream>>>(x32, U(X32), 2208, 320, 4416, 2208);
    repack_w_k<<<1812, 256, 0, stream>>>(conv2_w, U(WSTEM), 1104, 2208, 0, 1104, 1120, 0, 0, 8, 3, 1104, 3360);
    conv_async_k<0, 4, 1, 1, 1, 3, 10, 32, 1104, 3360, 1120, 8, 3, 4416, 2208, 0, 1, 4, false, false>
        <<<dim3(6, 23, 16), 256, 0, stream>>>(U(X32), nullptr, U(WSTEM), nullptr,
            nullptr, nullptr, nullptr, zp, nullptr, Pf, 1104);
    repack_w_k<<<1812, 256, 0, stream>>>(conv2_w, U(WSTEM), 1104, 2208, 1104, 1104, 1120, 0, 0, 8, 3, 1104, 3360);
    conv_async_k<0, 4, 1, 1, 1, 3, 10, 32, 1104, 3360, 1120, 8, 3, 4416, 2208, 1104, 1, 4, false, true>
        <<<dim3(6, 23, 16), 256, 0, stream>>>(U(X32), nullptr, U(WSTEM), nullptr,
            nullptr, nullptr, nullptr, zp, nullptr, Pf, 1104);
    reduce_k<4, 12, 10, 32, 1104, false><<<1380, 256, 0, stream>>>(Pf, conv2_b, U(XD0), 1104);
    // ---- phase B repacks (WSTEM/X32 regions now dead) ----
    repack_w_k<<<1269, 256, 0, stream>>>(up1_w, U(WUP1), 552, 1488, 0, 1104, 1120, 1104, 384, 384, 3, 576, 4512);
    repack_x_k<true><<<dim3(20, 12, 4), 256, 0, stream>>>(x16, U(X16), 384, 1280, 768, 384);
    repack_w_k<<<324, 256, 0, stream>>>(up2_w, U(WUP2), 276, 744, 0, 552, 576, 552, 192, 192, 3, 288, 2304);
    repack_w_k<<<27, 256, 0, stream>>>(up3_w, U(WUP3), 138, 372, 0, 276, 288, 276, 96, 96, 1, 144, 384);
    repack_x_k<true><<<dim3(80, 6, 4), 256, 0, stream>>>(x8, U(X8), 192, 5120, 384, 192);
    repack_wv_k<<<20, 256, 0, stream>>>(w1_w, w1ll_w, wv1, 552, 552);
    repack_wv_k<<<10, 256, 0, stream>>>(w2_w, nullptr, wv2, 276, 280);
    repack_wv_k<<<6, 256, 0, stream>>>(w3_w, nullptr, wv3, 138, 144);
    // ---- up1 (split-K 2, NOC32 async) ----
    conv_async_k<1, 2, 2, 2, 1, 2, 20, 64, 576, 4512, 1120, 384, 3, 2208, 1104, 0, 768, 2, false, false>
        <<<dim3(10, 18, 8), 256, 0, stream>>>(U(XD0), U(X16), U(WUP1), nullptr,
            nullptr, nullptr, nullptr, zp, nullptr, Pf, 552);
    reduce_k<2, 20, 20, 64, 576, true><<<2880, 256, 0, stream>>>(Pf, up1_b, U(XD1), 552);
    repack_x_k<false><<<dim3(320, 3, 4), 256, 0, stream>>>(x4, U(X4), 96, 20480, 96, 0);
    // ---- wave1 + level-1 masks ----
    wave_cl_k<69, 1152, 576, 20, 64, false, true><<<1280, 256, 0, stream>>>(
        U(XD1), wv1, w1_b, w1ll_b, nullptr, 4.f, h1, ll1);
    idwt_k<20, 64><<<20, 256, 0, stream>>>(ll1, h1, llb);
    minmax_k<<<1, 256, 0, stream>>>(llb, 20480, f32 + O_RED);
    mask_k<20, 64><<<20, 256, 0, stream>>>(h1, f32 + O_RED, mask1);
    dilate_k<20, 64, 2><<<20, 256, 0, stream>>>(mask1, upm1);
    masksfull_k<20, 64><<<80, 256, 0, stream>>>(mask1, cam1, wm1);
    // ---- up2 (NOC32 async, masked) ----
    conv_async_k<2, 2, 2, 2, 1, 2, 40, 128, 288, 2304, 576, 192, 3, 1152, 576, 0, 384, 1, true, false>
        <<<dim3(40, 9, 4), 256, 0, stream>>>(U(XD1), U(X8), U(WUP2), up2_b,
            upm1, cam1, wm1, zp, U(XAOF), nullptr, 276);
    // ---- wave2 + level-0 masks ----
    wave_cl_k<35, 576, 288, 40, 128, false, false><<<5120, 256, 0, stream>>>(
        U(XAOF), wv2, w2_b, nullptr, mask1, 2.f, h2, nullptr);
    idwt_k<40, 128><<<80, 256, 0, stream>>>(llb, h2, llc);
    minmax_k<<<1, 256, 0, stream>>>(llc, 81920, f32 + O_RED + 1);
    mask_k<40, 128><<<80, 256, 0, stream>>>(h2, f32 + O_RED + 1, mask2);
    dilate_k<40, 128, 2><<<80, 256, 0, stream>>>(mask2, upm2);
    masksfull_k<40, 128><<<320, 256, 0, stream>>>(mask2, cam2, wm2);
    // ---- up3 (single bf16, NOC16 async, masked) ----
    conv_async_k<2, 2, 2, 2, 1, 1, 80, 256, 144, 384, 288, 96, 1, 576, 288, 0, 96, 1, false, false>
        <<<dim3(160, 9, 4), 256, 0, stream>>>(U(XAOF), U(X4), U(WUP3), up3_b,
            upm2, cam2, wm2, zp, U(XB), nullptr, 138);
    // ---- wave3 + final idwt ----
    wave_cl_k<18, 144, 0, 80, 256, true, false><<<20480, 256, 0, stream>>>(
        U(XB), wv3, w3_b, nullptr, mask2, 1.f, h3, nullptr);
    idwt_k<80, 256><<<320, 256, 0, stream>>>(llc, h3, (float*)d_out);
}

// Round 5
// 2291.319 us; speedup vs baseline: 1.1516x; 1.0309x over previous
//
#include <hip/hip_runtime.h>
#include <hip/hip_bf16.h>
#include <stdint.h>

// ---------------------------------------------------------------------------
// SparseDecoderWave — MFMA bf16 implicit-GEMM, 3-segment K-stacked split.
// K layout per conv: [A_hi | A_lo | A_hi] x [W_hi | W_hi | W_lo]  (SEG=3)
//   => ah*wh + al*wh + ah*wl  (full double-bf16 cross terms, err ~2^-16).
// up3 is single-bf16 (SEG=1).
// Staging: T3 2-phase async — double-buffered LDS, global_load_lds (16B),
//   one barrier per k-chunk. XOR slot swizzle on the GLOBAL source permutation
//   (linear LDS dest); swizzled reads (0 bank conflicts). Masked (MODE 2) /
//   pad lanes redirect src address to a 16KB zero page. Chunked XCD swizzle,
//   oc slowest (r4: FETCH 1.05GB->204MB).
// R5: convs are LDS-BW-bound (read port ~98%: 240 b128*12cyc + staging writes
//   ≈ 3.6k of 3.7k cyc/chunk-slot). Grow per-wave tiles (WROWS 1-2 -> 2-4):
//   reads/MFMA stem 1.33->0.72, up1/up2 0.83->0.50, up3 1.17->0.75.
//   stem/up1/up2 -> 81.9KB LDS, 1 block/CU (MINW=1); up3 63.5KB, 2/CU.
//   Pf uses compact H-stride + row guard (BROWS may not divide H).
// ---------------------------------------------------------------------------

typedef float f32x4 __attribute__((ext_vector_type(4)));
typedef short s16x8 __attribute__((ext_vector_type(8)));

typedef const __attribute__((address_space(1))) void* gas_ptr;
typedef __attribute__((address_space(3))) void* las_ptr;

__device__ __forceinline__ void gl_lds16(const void* g, void* l) {
    __builtin_amdgcn_global_load_lds((gas_ptr)g, (las_ptr)l, 16, 0, 0);
}

__device__ __forceinline__ ushort f2bf(float f) {
    uint32_t u = __float_as_uint(f);
    u += 0x7FFFu + ((u >> 16) & 1u);
    return (ushort)(u >> 16);
}
__device__ __forceinline__ float bf2f(ushort h) {
    return __uint_as_float(((uint32_t)h) << 16);
}

// ---- zero page + XD0 head guard init (idempotent, runs each launch) ----
__global__ __launch_bounds__(256)
void zero_k(ushort* __restrict__ zp, ushort* __restrict__ xd0head)
{
    const int t = threadIdx.x;
    const uint4 z = {0, 0, 0, 0};
    for (int i = t; i < 1024; i += 256) *(uint4*)(zp + i * 8) = z;  // 16 KB
    if (t < 16) *(uint4*)(xd0head + t * 8) = z;                     // 256 B
}

// ---- weight repack: w[oc][ct][3][3] fp32 -> W'[t][OCP][KT] bf16 ----
__global__ __launch_bounds__(256)
void repack_w_k(const float* __restrict__ w, ushort* __restrict__ out,
                int OC, int CT, int ICOFF, int CAR, int CAP, int CAT,
                int CBR, int CBP, int SEG, int OCP, int KT)
{
    const int KG = KT / 8;
    const int u = blockIdx.x * 256 + threadIdx.x;
    if (u >= OCP * KG) return;
    const int oc = u / KG, kg = u - oc * KG;
    const int k0 = kg * 8;
    int ic, lo; bool ok;
    if (k0 < SEG * CAP) {
        const int seg = k0 / CAP, c = k0 - seg * CAP;
        lo = (seg == 2); ic = ICOFF + c; ok = (c < CAR);
    } else {
        const int kb = k0 - SEG * CAP;
        const int seg = kb / CBP, c = kb - seg * CBP;
        lo = (seg == 2); ic = CAT + c; ok = (c < CBR);
    }
    ok = ok && (oc < OC);
    for (int t = 0; t < 9; ++t) {
        ushort q[8];
#pragma unroll
        for (int j = 0; j < 8; ++j) q[j] = 0;
        if (ok) {
#pragma unroll
            for (int j = 0; j < 8; ++j) {
                const float v = w[((size_t)oc * CT + ic + j) * 9 + t];
                const ushort h = f2bf(v);
                q[j] = lo ? f2bf(v - bf2f(h)) : h;
            }
        }
        *(uint4*)(out + ((size_t)t * OCP + oc) * KT + k0) = *(uint4*)q;
    }
}

// ---- input repack: [b][c][p] fp32 -> [b][p][OST] bf16 hi(+lo at LOOFF) ----
template<bool SPLIT>
__global__ __launch_bounds__(256)
void repack_x_k(const float* __restrict__ in, ushort* __restrict__ out,
                int C, int HW, int OST, int LOOFF)
{
    __shared__ float tile[32][65];
    const int b = blockIdx.z, c0 = blockIdx.y * 32, p0 = blockIdx.x * 64;
    for (int e = threadIdx.x; e < 2048; e += 256) {
        const int cl = e >> 6, pl = e & 63;
        tile[cl][pl] = in[((size_t)b * C + c0 + cl) * HW + p0 + pl];
    }
    __syncthreads();
    const int pl = threadIdx.x >> 2, cg = (threadIdx.x & 3) * 8;
    ushort hv[8], lv[8];
#pragma unroll
    for (int j = 0; j < 8; ++j) {
        const float v = tile[cg + j][pl];
        const ushort h = f2bf(v);
        hv[j] = h;
        lv[j] = f2bf(v - bf2f(h));
    }
    const size_t o = ((size_t)b * HW + p0 + pl) * OST + c0 + cg;
    *(uint4*)(out + o) = *(uint4*)hv;
    if constexpr (SPLIT) *(uint4*)(out + LOOFF + o) = *(uint4*)lv;
}

// ---- async MFMA conv3x3: double-buffered LDS, global_load_lds staging ----
// MODE 0: edge pad (stem); MODE 1: reflect, A up2x (up1);
// MODE 2: reflect, A up2x, mask-redirected staging + leaky*wvm epilogue.
template<int MODE, int WR, int WC, int WROWS, int WCOLF, int NOCF,
         int H, int W, int OCP, int KT, int CAP, int CBP, int SEG,
         int ASTR, int APLSTR, int AOFF, int BSTR, int KS, int MINW,
         bool SOUT, bool ACCIN>
__global__ __launch_bounds__(256, MINW)
void conv_async_k(const ushort* __restrict__ xA, const ushort* __restrict__ xB,
                  const ushort* __restrict__ wgt, const float* __restrict__ bias,
                  const float* __restrict__ upm, const float* __restrict__ cam,
                  const float* __restrict__ wvm, const ushort* __restrict__ zpad,
                  ushort* __restrict__ outb, float* __restrict__ outp, int OC)
{
    constexpr int BROWS = WR * WROWS;
    constexpr int BCOLS = WC * WCOLF * 16;
    constexpr int NOC = NOCF * 16;
    constexpr int PH = BROWS + 2, PW = BCOLS + 2;
    constexpr int NPX = PH * PW;
    constexpr int NAU = NPX * 4;                    // A 16B slots
    constexpr int ASL = ((NAU + 63) / 64) * 64;     // wave-padded
    constexpr int NWU = 9 * NOC * 4;                // W 16B slots (mult of 64)
    constexpr int NSA = (ASL + 255) / 256;
    constexpr int NSW = (NWU + 255) / 256;
    constexpr int PERBUF = (ASL + NWU) * 8;         // ushorts per buffer
    constexpr int NCH = KT / 32;
    constexpr int XT = W / BCOLS;
    constexpr int HA = (MODE == 0) ? H : H / 2;
    constexpr int WA = (MODE == 0) ? W : W / 2;
    constexpr bool HASB = (SEG * CAP < KT);
    constexpr bool RGUARD = (H % BROWS) != 0;       // pad rows exist

    __shared__ __align__(16) ushort lds[2 * PERBUF];

    const int tid = threadIdx.x;

    // ---- chunked XCD swizzle (tot % 8 == 0 for all launches): oc slowest
    const int GX = gridDim.x, GY = gridDim.y, GZ = gridDim.z;
    const int L = blockIdx.x + GX * (blockIdx.y + GY * blockIdx.z);
    const int cpx = (GX * GY * GZ) >> 3;
    const int wsw = (L & 7) * cpx + (L >> 3);
    const int bky = wsw / (GX * GZ);
    const int rem = wsw - bky * (GX * GZ);
    const int bkz = rem / GX;
    const int bkx = rem - bkz * GX;

    const int b = bkz / KS, sid = bkz % KS;
    const int oc0 = bky * NOC;
    const int y0 = (bkx / XT) * BROWS;
    const int x0 = (bkx % XT) * BCOLS;
    const int lane = tid & 63, wv = tid >> 6;
    const int wr = wv / WC, wc = wv % WC;
    const int lq = lane >> 4, ln = lane & 15;
    const int wcb = wc * (WCOLF * 16);
    const int c0 = (sid * NCH) / KS, c1 = ((sid + 1) * NCH) / KS;
    const int wbv = wv * 512;                       // wave slot base (ushorts)

    // ---- A staging geometry (k-independent, source-permuted by swizzle) ----
    const ushort* pAp[NSA]; const ushort* pBp[NSA]; int aKO[NSA];
    for (int s = 0; s < NSA; ++s) {
        const int u = tid + s * 256;
        const int pp = u >> 2, sl = u & 3;
        aKO[s] = (sl ^ ((pp >> 1) & 3)) * 8;        // pre-swizzled k-group
        const bool val = pp < NPX;
        const int ppc = val ? pp : 0;
        const int py = ppc / PW, px = ppc - py * PW;
        int y = y0 + py - 1, x = x0 + px - 1;
        if (MODE == 0) { y = min(max(y, 0), H - 1); x = min(max(x, 0), W - 1); }
        else { y = (y < 0) ? -y : ((y >= H) ? 2 * H - 2 - y : y);
               x = (x < 0) ? -x : ((x >= W) ? 2 * W - 2 - x : x); }
        const int ya = (MODE == 0) ? y : (y >> 1);
        const int xa = (MODE == 0) ? x : (x >> 1);
        bool okA = val, okB = val;
        if (MODE == 2) {
            const float cm = cam[((size_t)b * H + y) * W + x];
            const float um = upm[((size_t)b * HA + ya) * WA + xa];
            okA = okA && (um * cm != 0.f);
            okB = okB && (cm != 0.f);
        }
        pAp[s] = okA ? xA + (size_t)((b * HA + ya) * WA + xa) * ASTR : zpad;
        if constexpr (HASB)
            pBp[s] = okB ? xB + (size_t)((b * H + y) * W + x) * BSTR : zpad;
        else
            pBp[s] = zpad;
    }
    // ---- W staging geometry ----
    const ushort* pWp[NSW];
    for (int s = 0; s < NSW; ++s) {
        const int u = tid + s * 256;
        const int wrow = u >> 2, sl = u & 3;
        const int kg = sl ^ ((wrow >> 1) & 3);      // pre-swizzled k-group
        const int t = wrow / NOC, ocl = wrow - t * NOC;  // true modulo
        pWp[s] = (u < NWU) ?
            wgt + (size_t)(t * OCP + oc0 + ocl) * KT + kg * 8 : zpad;
    }

    auto stage = [&](int buf, int kc) {
        ushort* ab = lds + buf * PERBUF;
        ushort* wb = ab + ASL * 8;
        const int ko = kc * 32;
#pragma unroll
        for (int s = 0; s < NSA; ++s) {
            if (s * 256 + wv * 64 < NAU) {          // wave-uniform skip
                const int k = ko + aKO[s];
                const ushort* g;
                if (!HASB || k < SEG * CAP) {
                    int ka = (SEG == 3 && k >= 2 * CAP) ? k - 2 * CAP : k;
                    const int pl = (ka >= CAP) ? 1 : 0;
                    g = pAp[s] + pl * APLSTR + AOFF + (ka - pl * CAP);
                } else {
                    int kb = k - SEG * CAP;
                    if (SEG == 3 && kb >= 2 * CBP) kb -= 2 * CBP;
                    g = pBp[s] + kb;
                }
                gl_lds16(g, ab + s * 2048 + wbv);
            }
        }
#pragma unroll
        for (int s = 0; s < NSW; ++s)
            if (s * 256 + wv * 64 < NWU)            // wave-uniform skip
                gl_lds16(pWp[s] + ko, wb + s * 2048 + wbv);
    };

    f32x4 acc[WROWS][WCOLF][NOCF];
#pragma unroll
    for (int i = 0; i < WROWS; ++i)
#pragma unroll
        for (int c = 0; c < WCOLF; ++c)
#pragma unroll
            for (int n = 0; n < NOCF; ++n) acc[i][c][n] = {0.f, 0.f, 0.f, 0.f};

    if (ACCIN) {
#pragma unroll
        for (int ri = 0; ri < WROWS; ++ri) {
            const int yy = y0 + wr * WROWS + ri;
            if (RGUARD && yy >= H) continue;        // pad row: keep acc 0
            const float* Pr = outp +
                ((((size_t)sid * 4 + b) * H + yy) * W + x0 + wcb) * OCP;
#pragma unroll
            for (int cf = 0; cf < WCOLF; ++cf)
#pragma unroll
                for (int n2 = 0; n2 < NOCF; ++n2)
#pragma unroll
                    for (int r = 0; r < 4; ++r)
                        acc[ri][cf][n2][r] =
                            Pr[(size_t)(cf * 16 + lq * 4 + r) * OCP + oc0 + n2 * 16 + ln];
        }
    }

    stage(0, c0);
    __syncthreads();                                 // vmcnt drain: buf0 ready
    int cur = 0;
    for (int kc = c0; kc < c1; ++kc) {
        if (kc + 1 < c1) stage(cur ^ 1, kc + 1);     // async into other buffer
        const ushort* at = lds + cur * PERBUF;
        const ushort* wt = at + ASL * 8;
        // ---- preload A fragments (swizzled reads, conflict-free) ----
        s16x8 afr[WROWS + 2][WCOLF][3];
#pragma unroll
        for (int ar = 0; ar < WROWS + 2; ++ar)
#pragma unroll
            for (int cf = 0; cf < WCOLF; ++cf)
#pragma unroll
                for (int dx = 0; dx < 3; ++dx) {
                    const int p = (wr * WROWS + ar) * PW + wcb + cf * 16 + ln + dx;
                    afr[ar][cf][dx] = *(const s16x8*)
                        &at[p * 32 + ((lq ^ ((p >> 1) & 3)) * 8)];
                }
        // ---- 9 taps ----
#pragma unroll
        for (int t = 0; t < 9; ++t) {
            const int dy = t / 3, dx = t - dy * 3;
#pragma unroll
            for (int n2 = 0; n2 < NOCF; ++n2) {
                const int wrow = t * NOC + n2 * 16 + ln;
                const s16x8 bw = *(const s16x8*)
                    &wt[wrow * 32 + ((lq ^ ((wrow >> 1) & 3)) * 8)];
#pragma unroll
                for (int ri = 0; ri < WROWS; ++ri)
#pragma unroll
                    for (int cf = 0; cf < WCOLF; ++cf)
                        acc[ri][cf][n2] = __builtin_amdgcn_mfma_f32_16x16x32_bf16(
                            afr[ri + dy][cf][dx], bw, acc[ri][cf][n2], 0, 0, 0);
            }
        }
        __syncthreads();   // drains lgkm (reads done) + vmcnt (next buf staged)
        cur ^= 1;
    }

    // ---- epilogue ----
    if (KS > 1) {
#pragma unroll
        for (int ri = 0; ri < WROWS; ++ri) {
            const int yy = y0 + wr * WROWS + ri;
            if (RGUARD && yy >= H) continue;        // pad row: discard
            float* Pr = outp +
                ((((size_t)sid * 4 + b) * H + yy) * W + x0 + wcb) * OCP;
#pragma unroll
            for (int cf = 0; cf < WCOLF; ++cf)
#pragma unroll
                for (int n2 = 0; n2 < NOCF; ++n2)
#pragma unroll
                    for (int r = 0; r < 4; ++r)
                        Pr[(size_t)(cf * 16 + lq * 4 + r) * OCP + oc0 + n2 * 16 + ln] =
                            acc[ri][cf][n2][r];
        }
    } else {
        constexpr int OST = SOUT ? 2 * OCP : OCP;
#pragma unroll
        for (int ri = 0; ri < WROWS; ++ri) {
            const int y = y0 + wr * WROWS + ri;
            if (RGUARD && y >= H) continue;
#pragma unroll
            for (int cf = 0; cf < WCOLF; ++cf)
#pragma unroll
                for (int n2 = 0; n2 < NOCF; ++n2) {
                    const int oc = oc0 + n2 * 16 + ln;
                    const float bv = (oc < OC) ? bias[oc] : 0.f;
#pragma unroll
                    for (int r = 0; r < 4; ++r) {
                        const int x = x0 + wcb + cf * 16 + lq * 4 + r;
                        float v = acc[ri][cf][n2][r] + bv;
                        v = v > 0.f ? v : 0.2f * v;
                        v *= wvm[((size_t)b * H + y) * W + x];
                        if (oc >= OC) v = 0.f;
                        const size_t o = (((size_t)b * H + y) * W + x) * OST + oc;
                        const ushort h = f2bf(v);
                        outb[o] = h;
                        if constexpr (SOUT) outb[o + OCP] = f2bf(v - bf2f(h));
                    }
                }
        }
    }
}

// ---- split-K reduce: sum fp32 partials, bias(+leaky), bf16 hi/lo store ----
template<int KS, int HP, int H, int W, int OCP, bool ACT>
__global__ __launch_bounds__(256)
void reduce_k(const float* __restrict__ P, const float* __restrict__ bias,
              ushort* __restrict__ out, int OC)
{
    constexpr int OG = OCP / 4;
    const int u = blockIdx.x * 256 + threadIdx.x;
    if (u >= 4 * H * W * OG) return;
    const int og = u % OG;
    const int px = u / OG;
    const int x = px % W, y = (px / W) % H, b = px / (W * H);
    float4 s = {0.f, 0.f, 0.f, 0.f};
    for (int sid = 0; sid < KS; ++sid) {
        const float4 v = *(const float4*)
            (P + ((((size_t)sid * 4 + b) * HP + y) * W + x) * OCP + og * 4);
        s.x += v.x; s.y += v.y; s.z += v.z; s.w += v.w;
    }
    const int oc = og * 4;
    const float vv[4] = {s.x, s.y, s.z, s.w};
    ushort hi[4], lo[4];
#pragma unroll
    for (int j = 0; j < 4; ++j) {
        float v = (oc + j < OC) ? vv[j] + bias[oc + j] : 0.f;
        if (ACT) v = v > 0.f ? v : 0.2f * v;
        const ushort h = f2bf(v);
        hi[j] = h;
        lo[j] = f2bf(v - bf2f(h));
    }
    const size_t o = (size_t)px * 2 * OCP + oc;
    *(uint2*)(out + o) = *(uint2*)hi;
    *(uint2*)(out + o + OCP) = *(uint2*)lo;
}

// ---- wave weight repack: wh[3][C][9](+wll[C][9]) -> Wv[t][CP][4] fp32 ----
__global__ __launch_bounds__(256)
void repack_wv_k(const float* __restrict__ wh, const float* __restrict__ wll,
                 float* __restrict__ out, int C, int CP)
{
    const int u = blockIdx.x * 256 + threadIdx.x;
    if (u >= 9 * CP) return;
    const int t = u / CP, ic = u - t * CP;
    float4 v = {0.f, 0.f, 0.f, 0.f};
    if (ic < C) {
        v.x = wh[((size_t)0 * C + ic) * 9 + t];
        v.y = wh[((size_t)1 * C + ic) * 9 + t];
        v.z = wh[((size_t)2 * C + ic) * 9 + t];
        if (wll) v.w = wll[(size_t)ic * 9 + t];
    }
    *(float4*)(out + (size_t)u * 4) = v;
}

// ---- wave convs from channel-last bf16 (hi at +0, lo at +LOOFF) ----
template<int G, int CSTR, int LOOFF, int H, int W, bool SIN, bool HAS_LL>
__global__ __launch_bounds__(256)
void wave_cl_k(const ushort* __restrict__ xq, const float* __restrict__ wv,
               const float* __restrict__ bh, const float* __restrict__ bll,
               const float* __restrict__ mhalf, float scale,
               float* __restrict__ outh, float* __restrict__ outll)
{
    const int lane = threadIdx.x & 63;
    const int pix = blockIdx.x * 4 + (threadIdx.x >> 6);
    const int x = pix % W, y = (pix / W) % H, b = pix / (W * H);
    float a0 = 0.f, a1 = 0.f, a2 = 0.f, a3 = 0.f;
    for (int it = lane; it < 9 * G; it += 64) {
        const int t = it / G, g = it - t * G;
        const int dy = t / 3 - 1, dx = t % 3 - 1;
        const int yy = y + dy, xx = x + dx;
        const int yc = min(max(yy, 0), H - 1), xc = min(max(xx, 0), W - 1);
        const bool inr = (yy >= 0) && (yy < H) && (xx >= 0) && (xx < W);
        const size_t base = (((size_t)b * H + yc) * W + xc) * CSTR + g * 8;
        const uint4 hv = *(const uint4*)(xq + base);
        uint4 lv = {0, 0, 0, 0};
        if constexpr (!SIN) lv = *(const uint4*)(xq + base + LOOFF);
        const float4* wp = (const float4*)(wv + ((size_t)t * (G * 8) + g * 8) * 4);
        const uint* hw = (const uint*)&hv;
        const uint* lw = (const uint*)&lv;
#pragma unroll
        for (int j = 0; j < 8; ++j) {
            const uint wd = hw[j >> 1];
            float xf = (j & 1) ? __uint_as_float(wd & 0xFFFF0000u)
                               : __uint_as_float(wd << 16);
            if constexpr (!SIN) {
                const uint wl = lw[j >> 1];
                xf += (j & 1) ? __uint_as_float(wl & 0xFFFF0000u)
                              : __uint_as_float(wl << 16);
            }
            const float xz = inr ? xf : 0.f;
            const float4 w4 = wp[j];
            a0 = fmaf(w4.x, xz, a0);
            a1 = fmaf(w4.y, xz, a1);
            a2 = fmaf(w4.z, xz, a2);
            if constexpr (HAS_LL) a3 = fmaf(w4.w, xf, a3);
        }
    }
#pragma unroll
    for (int o = 1; o < 64; o <<= 1) {
        a0 += __shfl_xor(a0, o);
        a1 += __shfl_xor(a1, o);
        a2 += __shfl_xor(a2, o);
        if constexpr (HAS_LL) a3 += __shfl_xor(a3, o);
    }
    if (lane == 0) {
        float wm = 1.f;
        if (mhalf) wm = mhalf[((size_t)b * (H / 2) + (y >> 1)) * (W / 2) + (x >> 1)];
        const size_t hb = (size_t)b * 3 * H * W + (size_t)y * W + x;
        outh[hb]             = (a0 + bh[0]) * scale * wm;
        outh[hb + H * W]     = (a1 + bh[1]) * scale * wm;
        outh[hb + 2 * H * W] = (a2 + bh[2]) * scale * wm;
        if constexpr (HAS_LL) outll[((size_t)b * H + y) * W + x] = (a3 + bll[0]) * 8.f;
    }
}

// ---- inverse Haar DWT ----
template<int H, int W>
__global__ __launch_bounds__(256)
void idwt_k(const float* __restrict__ ll, const float* __restrict__ h,
            float* __restrict__ out)
{
    const int g = blockIdx.x * 256 + threadIdx.x;
    if (g >= 4 * H * W) return;
    const int x = g % W, y = (g / W) % H, b = g / (W * H);
    const float l  = ll[g];
    const float lh = h[((size_t)(b * 3 + 0) * H + y) * W + x];
    const float hl = h[((size_t)(b * 3 + 1) * H + y) * W + x];
    const float hh = h[((size_t)(b * 3 + 2) * H + y) * W + x];
    const float x00 = (l + lh + hl + hh) * 0.5f;
    const float x01 = (l - lh + hl - hh) * 0.5f;
    const float x10 = (l + lh - hl - hh) * 0.5f;
    const float x11 = (l - lh - hl + hh) * 0.5f;
    float* ob = out + (size_t)b * (2 * H) * (2 * W);
    ob[(size_t)(2 * y) * (2 * W) + 2 * x]         = x00;
    ob[(size_t)(2 * y) * (2 * W) + 2 * x + 1]     = x01;
    ob[(size_t)(2 * y + 1) * (2 * W) + 2 * x]     = x10;
    ob[(size_t)(2 * y + 1) * (2 * W) + 2 * x + 1] = x11;
}

__global__ __launch_bounds__(256)
void minmax_k(const float* __restrict__ p, int n, float* __restrict__ thr)
{
    __shared__ float smax[256], smin[256];
    float mx = -1e30f, mn = 1e30f;
    for (int i = threadIdx.x; i < n; i += 256) {
        const float v = p[i];
        mx = fmaxf(mx, v);
        mn = fminf(mn, v);
    }
    smax[threadIdx.x] = mx;
    smin[threadIdx.x] = mn;
    __syncthreads();
    for (int s = 128; s > 0; s >>= 1) {
        if (threadIdx.x < s) {
            smax[threadIdx.x] = fmaxf(smax[threadIdx.x], smax[threadIdx.x + s]);
            smin[threadIdx.x] = fminf(smin[threadIdx.x], smin[threadIdx.x + s]);
        }
        __syncthreads();
    }
    if (threadIdx.x == 0) *thr = (smax[0] - smin[0]) * 0.1f;
}

template<int H, int W>
__global__ __launch_bounds__(256)
void mask_k(const float* __restrict__ h, const float* __restrict__ thr,
            float* __restrict__ mask)
{
    const int g = blockIdx.x * 256 + threadIdx.x;
    if (g >= 4 * H * W) return;
    const int x = g % W, y = (g / W) % H, b = g / (W * H);
    const float t  = *thr;
    const float v0 = fabsf(h[((size_t)(b * 3 + 0) * H + y) * W + x]);
    const float v1 = fabsf(h[((size_t)(b * 3 + 1) * H + y) * W + x]);
    const float v2 = fabsf(h[((size_t)(b * 3 + 2) * H + y) * W + x]);
    mask[g] = (fmaxf(v0, fmaxf(v1, v2)) > t) ? 1.f : 0.f;
}

template<int H, int W, int R>
__global__ __launch_bounds__(256)
void dilate_k(const float* __restrict__ m, float* __restrict__ o)
{
    const int g = blockIdx.x * 256 + threadIdx.x;
    if (g >= 4 * H * W) return;
    const int x = g % W, y = (g / W) % H, b = g / (W * H);
    float v = 0.f;
    for (int dy = -R; dy <= R; ++dy) {
        const int yy = y + dy;
        if (yy < 0 || yy >= H) continue;
        for (int dx = -R; dx <= R; ++dx) {
            const int xx = x + dx;
            if (xx < 0 || xx >= W) continue;
            v = fmaxf(v, m[((size_t)b * H + yy) * W + xx]);
        }
    }
    o[g] = (v > 0.f) ? 1.f : 0.f;
}

template<int H, int W>
__global__ __launch_bounds__(256)
void masksfull_k(const float* __restrict__ m, float* __restrict__ conva,
                 float* __restrict__ wavem)
{
    const int g = blockIdx.x * 256 + threadIdx.x;
    constexpr int H2 = 2 * H, W2 = 2 * W;
    if (g >= 4 * H2 * W2) return;
    const int x = g % W2, y = (g / W2) % H2, b = g / (W2 * H2);
    float c5 = 0.f, c3 = 0.f;
    for (int dy = -2; dy <= 2; ++dy) {
        const int yy = y + dy;
        if (yy < 0 || yy >= H2) continue;
        const int my = yy >> 1;
        for (int dx = -2; dx <= 2; ++dx) {
            const int xx = x + dx;
            if (xx < 0 || xx >= W2) continue;
            const float v = m[((size_t)b * H + my) * W + (xx >> 1)];
            c5 = fmaxf(c5, v);
            if (dy >= -1 && dy <= 1 && dx >= -1 && dx <= 1) c3 = fmaxf(c3, v);
        }
    }
    conva[g] = (c5 > 0.f) ? 1.f : 0.f;
    wavem[g] = (c3 > 0.f) ? 1.f : 0.f;
}

// ---------------------------------------------------------------------------
// workspace layout (bytes)
// ---------------------------------------------------------------------------
static constexpr size_t WSTEM = 0;             // 66,769,920 (9*1104*3360*2), both phases
static constexpr size_t WUP1  = 0;             // 46,780,416 (9*576*4512*2)
static constexpr size_t X16   = 46780416ull;   // 7,864,320
static constexpr size_t WUP2  = 54644736ull;   // 11,943,936 (9*288*2304*2) end 66,588,672
static constexpr size_t XB    = 0ull;          // 23,592,960 (over WUP1, dead)
static constexpr size_t X4    = 23592960ull;   // 15,728,640 (over WUP1, dead) end 39,321,600
static constexpr size_t WUP3  = 66769920ull;   // 995,328  (over X32, dead)
static constexpr size_t WV1   = 67765248ull;   // 79,488
static constexpr size_t WV2   = 67844736ull;   // 40,320
static constexpr size_t WV3   = 67885056ull;   // 20,736 end 67,905,792
static constexpr size_t X32   = 66769920ull;   // 11,304,960 end 78,074,880
static constexpr size_t XD0   = 78074880ull;   // 5,652,480  end 83,727,360
static constexpr size_t ZPADO = 83727360ull;   // 16,384 zero page (A/W redirect + X32 tail guard)
static constexpr size_t PF    = 83743744ull;   // stem P 22.6M / up1 P 23.6M (H-stride, compact)
static constexpr size_t XAOF  = 83743744ull;   // 23,592,960 end 107,336,704
static constexpr size_t XD1   = 110859264ull;  // 11,796,480 end 122,655,744
static constexpr size_t X8    = 122655744ull;  // 15,728,640 end 138,384,384
static constexpr size_t F32B  = 138384384ull;
static constexpr size_t O_LL1 = 0, O_H1 = 5120, O_LLB = 20480, O_H2 = 40960;
static constexpr size_t O_LLC = 102400, O_H3 = 184320, O_M1 = 430080;
static constexpr size_t O_UPM1 = 435200, O_CAM1 = 440320, O_WM1 = 460800;
static constexpr size_t O_M2 = 481280, O_UPM2 = 501760, O_CAM2 = 522240;
static constexpr size_t O_WM2 = 604160, O_RED = 686080;

extern "C" void kernel_launch(void* const* d_in, const int* in_sizes, int n_in,
                              void* d_out, int out_size, void* d_ws, size_t ws_size,
                              hipStream_t stream)
{
    const float* x32     = (const float*)d_in[0];
    const float* x16     = (const float*)d_in[1];
    const float* x8      = (const float*)d_in[2];
    const float* x4      = (const float*)d_in[3];
    const float* conv2_w = (const float*)d_in[4];
    const float* conv2_b = (const float*)d_in[5];
    const float* up1_w   = (const float*)d_in[6];
    const float* up1_b   = (const float*)d_in[7];
    const float* w1ll_w  = (const float*)d_in[8];
    const float* w1ll_b  = (const float*)d_in[9];
    const float* w1_w    = (const float*)d_in[10];
    const float* w1_b    = (const float*)d_in[11];
    const float* up2_w   = (const float*)d_in[12];
    const float* up2_b   = (const float*)d_in[13];
    const float* w2_w    = (const float*)d_in[14];
    const float* w2_b    = (const float*)d_in[15];
    const float* up3_w   = (const float*)d_in[16];
    const float* up3_b   = (const float*)d_in[17];
    const float* w3_w    = (const float*)d_in[18];
    const float* w3_b    = (const float*)d_in[19];

    char* ws = (char*)d_ws;
    auto U = [&](size_t off) { return (ushort*)(ws + off); };
    float* Pf  = (float*)(ws + PF);
    float* f32 = (float*)(ws + F32B);
    float* ll1   = f32 + O_LL1;
    float* h1    = f32 + O_H1;
    float* llb   = f32 + O_LLB;
    float* h2    = f32 + O_H2;
    float* llc   = f32 + O_LLC;
    float* h3    = f32 + O_H3;
    float* mask1 = f32 + O_M1;
    float* upm1  = f32 + O_UPM1;
    float* cam1  = f32 + O_CAM1;
    float* wm1   = f32 + O_WM1;
    float* mask2 = f32 + O_M2;
    float* upm2  = f32 + O_UPM2;
    float* cam2  = f32 + O_CAM2;
    float* wm2   = f32 + O_WM2;
    float* wv1   = (float*)(ws + WV1);
    float* wv2   = (float*)(ws + WV2);
    float* wv3   = (float*)(ws + WV3);
    const ushort* zp = U(ZPADO);

    // ---- zero page + XD0 head guard ----
    zero_k<<<1, 256, 0, stream>>>(U(ZPADO), U(XD0));

    // ---- stem: 2 IC-phases, split-K 4; tile 4x32, NOC48, 1 blk/CU ----
    repack_x_k<true><<<dim3(5, 69, 4), 256, 0, stream>>>(x32, U(X32), 2208, 320, 4416, 2208);
    repack_w_k<<<1812, 256, 0, stream>>>(conv2_w, U(WSTEM), 1104, 2208, 0, 1104, 1120, 0, 0, 8, 3, 1104, 3360);
    conv_async_k<0, 2, 2, 2, 1, 3, 10, 32, 1104, 3360, 1120, 8, 3, 4416, 2208, 0, 1, 4, 1, false, false>
        <<<dim3(3, 23, 16), 256, 0, stream>>>(U(X32), nullptr, U(WSTEM), nullptr,
            nullptr, nullptr, nullptr, zp, nullptr, Pf, 1104);
    repack_w_k<<<1812, 256, 0, stream>>>(conv2_w, U(WSTEM), 1104, 2208, 1104, 1104, 1120, 0, 0, 8, 3, 1104, 3360);
    conv_async_k<0, 2, 2, 2, 1, 3, 10, 32, 1104, 3360, 1120, 8, 3, 4416, 2208, 1104, 1, 4, 1, false, true>
        <<<dim3(3, 23, 16), 256, 0, stream>>>(U(X32), nullptr, U(WSTEM), nullptr,
            nullptr, nullptr, nullptr, zp, nullptr, Pf, 1104);
    reduce_k<4, 10, 10, 32, 1104, false><<<1380, 256, 0, stream>>>(Pf, conv2_b, U(XD0), 1104);
    // ---- phase B repacks ----
    repack_w_k<<<1269, 256, 0, stream>>>(up1_w, U(WUP1), 552, 1488, 0, 1104, 1120, 1104, 384, 384, 3, 576, 4512);
    repack_x_k<true><<<dim3(20, 12, 4), 256, 0, stream>>>(x16, U(X16), 384, 1280, 768, 384);
    repack_w_k<<<324, 256, 0, stream>>>(up2_w, U(WUP2), 276, 744, 0, 552, 576, 552, 192, 192, 3, 288, 2304);
    repack_w_k<<<27, 256, 0, stream>>>(up3_w, U(WUP3), 138, 372, 0, 276, 288, 276, 96, 96, 1, 144, 384);
    repack_x_k<true><<<dim3(80, 6, 4), 256, 0, stream>>>(x8, U(X8), 192, 5120, 384, 192);
    repack_wv_k<<<20, 256, 0, stream>>>(w1_w, w1ll_w, wv1, 552, 552);
    repack_wv_k<<<10, 256, 0, stream>>>(w2_w, nullptr, wv2, 276, 280);
    repack_wv_k<<<6, 256, 0, stream>>>(w3_w, nullptr, wv3, 138, 144);
    // ---- up1 (split-K 2; tile 8x32, NOC32, 1 blk/CU; rows 20-23 guarded) ----
    conv_async_k<1, 2, 2, 4, 1, 2, 20, 64, 576, 4512, 1120, 384, 3, 2208, 1104, 0, 768, 2, 1, false, false>
        <<<dim3(6, 18, 8), 256, 0, stream>>>(U(XD0), U(X16), U(WUP1), nullptr,
            nullptr, nullptr, nullptr, zp, nullptr, Pf, 552);
    reduce_k<2, 20, 20, 64, 576, true><<<2880, 256, 0, stream>>>(Pf, up1_b, U(XD1), 552);
    repack_x_k<false><<<dim3(320, 3, 4), 256, 0, stream>>>(x4, U(X4), 96, 20480, 96, 0);
    // ---- wave1 + level-1 masks ----
    wave_cl_k<69, 1152, 576, 20, 64, false, true><<<1280, 256, 0, stream>>>(
        U(XD1), wv1, w1_b, w1ll_b, nullptr, 4.f, h1, ll1);
    idwt_k<20, 64><<<20, 256, 0, stream>>>(ll1, h1, llb);
    minmax_k<<<1, 256, 0, stream>>>(llb, 20480, f32 + O_RED);
    mask_k<20, 64><<<20, 256, 0, stream>>>(h1, f32 + O_RED, mask1);
    dilate_k<20, 64, 2><<<20, 256, 0, stream>>>(mask1, upm1);
    masksfull_k<20, 64><<<80, 256, 0, stream>>>(mask1, cam1, wm1);
    // ---- up2 (tile 8x32, NOC32, 1 blk/CU, masked) ----
    conv_async_k<2, 2, 2, 4, 1, 2, 40, 128, 288, 2304, 576, 192, 3, 1152, 576, 0, 384, 1, 1, true, false>
        <<<dim3(20, 9, 4), 256, 0, stream>>>(U(XD1), U(X8), U(WUP2), up2_b,
            upm1, cam1, wm1, zp, U(XAOF), nullptr, 276);
    // ---- wave2 + level-0 masks ----
    wave_cl_k<35, 576, 288, 40, 128, false, false><<<5120, 256, 0, stream>>>(
        U(XAOF), wv2, w2_b, nullptr, mask1, 2.f, h2, nullptr);
    idwt_k<40, 128><<<80, 256, 0, stream>>>(llb, h2, llc);
    minmax_k<<<1, 256, 0, stream>>>(llc, 81920, f32 + O_RED + 1);
    mask_k<40, 128><<<80, 256, 0, stream>>>(h2, f32 + O_RED + 1, mask2);
    dilate_k<40, 128, 2><<<80, 256, 0, stream>>>(mask2, upm2);
    masksfull_k<40, 128><<<320, 256, 0, stream>>>(mask2, cam2, wm2);
    // ---- up3 (single bf16; tile 8x32, NOC16, 2 blk/CU, masked) ----
    conv_async_k<2, 2, 2, 4, 1, 1, 80, 256, 144, 384, 288, 96, 1, 576, 288, 0, 96, 1, 2, false, false>
        <<<dim3(80, 9, 4), 256, 0, stream>>>(U(XAOF), U(X4), U(WUP3), up3_b,
            upm2, cam2, wm2, zp, U(XB), nullptr, 138);
    // ---- wave3 + final idwt ----
    wave_cl_k<18, 144, 0, 80, 256, true, false><<<20480, 256, 0, stream>>>(
        U(XB), wv3, w3_b, nullptr, mask2, 1.f, h3, nullptr);
    idwt_k<80, 256><<<320, 256, 0, stream>>>(llc, h3, (float*)d_out);
}

// Round 6
// 2223.756 us; speedup vs baseline: 1.1865x; 1.0304x over previous
//
#include <hip/hip_runtime.h>
#include <hip/hip_bf16.h>
#include <stdint.h>

// ---------------------------------------------------------------------------
// SparseDecoderWave — MFMA bf16 implicit-GEMM, 3-segment K-stacked split.
// K layout per conv: [A_hi | A_lo | A_hi] x [W_hi | W_hi | W_lo]  (SEG=3)
//   => ah*wh + al*wh + ah*wl  (full double-bf16 cross terms, err ~2^-16).
// up3 is single-bf16 (SEG=1).
// Staging: T3 2-phase async — double-buffered LDS, global_load_lds (16B),
//   one barrier per k-chunk. XOR slot swizzle on the GLOBAL source permutation
//   (linear LDS dest); swizzled reads (0 bank conflicts). Masked (MODE 2) /
//   pad lanes redirect src address to a 16KB zero page. Chunked XCD swizzle,
//   oc slowest (r4: FETCH 1.05GB->204MB). Big per-wave tiles (r5).
// R6: staging addresses are piecewise-AFFINE in kc with chunk-aligned
//   breakpoints (CAP/SEG*CAP/CBP all %32==0). Keep per-slot running
//   pointers, advance +=32 ushorts/chunk (~22 VALU), full re-derivation
//   only at run boundaries (~3-5/kernel). r5 recomputed ~150 VALU/thread
//   per chunk under exec-masked per-lane branches (VALUBusy 26%).
//   Also __launch_bounds__(256,2): 2x81920 = exactly 160KiB/CU.
// ---------------------------------------------------------------------------

typedef float f32x4 __attribute__((ext_vector_type(4)));
typedef short s16x8 __attribute__((ext_vector_type(8)));

typedef const __attribute__((address_space(1))) void* gas_ptr;
typedef __attribute__((address_space(3))) void* las_ptr;

__device__ __forceinline__ void gl_lds16(const void* g, void* l) {
    __builtin_amdgcn_global_load_lds((gas_ptr)g, (las_ptr)l, 16, 0, 0);
}

__device__ __forceinline__ ushort f2bf(float f) {
    uint32_t u = __float_as_uint(f);
    u += 0x7FFFu + ((u >> 16) & 1u);
    return (ushort)(u >> 16);
}
__device__ __forceinline__ float bf2f(ushort h) {
    return __uint_as_float(((uint32_t)h) << 16);
}

// ---- zero page + XD0 head guard init (idempotent, runs each launch) ----
__global__ __launch_bounds__(256)
void zero_k(ushort* __restrict__ zp, ushort* __restrict__ xd0head)
{
    const int t = threadIdx.x;
    const uint4 z = {0, 0, 0, 0};
    for (int i = t; i < 1024; i += 256) *(uint4*)(zp + i * 8) = z;  // 16 KB
    if (t < 16) *(uint4*)(xd0head + t * 8) = z;                     // 256 B
}

// ---- weight repack: w[oc][ct][3][3] fp32 -> W'[t][OCP][KT] bf16 ----
__global__ __launch_bounds__(256)
void repack_w_k(const float* __restrict__ w, ushort* __restrict__ out,
                int OC, int CT, int ICOFF, int CAR, int CAP, int CAT,
                int CBR, int CBP, int SEG, int OCP, int KT)
{
    const int KG = KT / 8;
    const int u = blockIdx.x * 256 + threadIdx.x;
    if (u >= OCP * KG) return;
    const int oc = u / KG, kg = u - oc * KG;
    const int k0 = kg * 8;
    int ic, lo; bool ok;
    if (k0 < SEG * CAP) {
        const int seg = k0 / CAP, c = k0 - seg * CAP;
        lo = (seg == 2); ic = ICOFF + c; ok = (c < CAR);
    } else {
        const int kb = k0 - SEG * CAP;
        const int seg = kb / CBP, c = kb - seg * CBP;
        lo = (seg == 2); ic = CAT + c; ok = (c < CBR);
    }
    ok = ok && (oc < OC);
    for (int t = 0; t < 9; ++t) {
        ushort q[8];
#pragma unroll
        for (int j = 0; j < 8; ++j) q[j] = 0;
        if (ok) {
#pragma unroll
            for (int j = 0; j < 8; ++j) {
                const float v = w[((size_t)oc * CT + ic + j) * 9 + t];
                const ushort h = f2bf(v);
                q[j] = lo ? f2bf(v - bf2f(h)) : h;
            }
        }
        *(uint4*)(out + ((size_t)t * OCP + oc) * KT + k0) = *(uint4*)q;
    }
}

// ---- input repack: [b][c][p] fp32 -> [b][p][OST] bf16 hi(+lo at LOOFF) ----
template<bool SPLIT>
__global__ __launch_bounds__(256)
void repack_x_k(const float* __restrict__ in, ushort* __restrict__ out,
                int C, int HW, int OST, int LOOFF)
{
    __shared__ float tile[32][65];
    const int b = blockIdx.z, c0 = blockIdx.y * 32, p0 = blockIdx.x * 64;
    for (int e = threadIdx.x; e < 2048; e += 256) {
        const int cl = e >> 6, pl = e & 63;
        tile[cl][pl] = in[((size_t)b * C + c0 + cl) * HW + p0 + pl];
    }
    __syncthreads();
    const int pl = threadIdx.x >> 2, cg = (threadIdx.x & 3) * 8;
    ushort hv[8], lv[8];
#pragma unroll
    for (int j = 0; j < 8; ++j) {
        const float v = tile[cg + j][pl];
        const ushort h = f2bf(v);
        hv[j] = h;
        lv[j] = f2bf(v - bf2f(h));
    }
    const size_t o = ((size_t)b * HW + p0 + pl) * OST + c0 + cg;
    *(uint4*)(out + o) = *(uint4*)hv;
    if constexpr (SPLIT) *(uint4*)(out + LOOFF + o) = *(uint4*)lv;
}

// ---- async MFMA conv3x3: double-buffered LDS, global_load_lds staging ----
// MODE 0: edge pad (stem); MODE 1: reflect, A up2x (up1);
// MODE 2: reflect, A up2x, mask-redirected staging + leaky*wvm epilogue.
template<int MODE, int WR, int WC, int WROWS, int WCOLF, int NOCF,
         int H, int W, int OCP, int KT, int CAP, int CBP, int SEG,
         int ASTR, int APLSTR, int AOFF, int BSTR, int KS, int MINW,
         bool SOUT, bool ACCIN>
__global__ __launch_bounds__(256, MINW)
void conv_async_k(const ushort* __restrict__ xA, const ushort* __restrict__ xB,
                  const ushort* __restrict__ wgt, const float* __restrict__ bias,
                  const float* __restrict__ upm, const float* __restrict__ cam,
                  const float* __restrict__ wvm, const ushort* __restrict__ zpad,
                  ushort* __restrict__ outb, float* __restrict__ outp, int OC)
{
    constexpr int BROWS = WR * WROWS;
    constexpr int BCOLS = WC * WCOLF * 16;
    constexpr int NOC = NOCF * 16;
    constexpr int PH = BROWS + 2, PW = BCOLS + 2;
    constexpr int NPX = PH * PW;
    constexpr int NAU = NPX * 4;                    // A 16B slots
    constexpr int ASL = ((NAU + 63) / 64) * 64;     // wave-padded
    constexpr int NWU = 9 * NOC * 4;                // W 16B slots (mult of 64)
    constexpr int NSA = (ASL + 255) / 256;
    constexpr int NSW = (NWU + 255) / 256;
    constexpr int PERBUF = (ASL + NWU) * 8;         // ushorts per buffer
    constexpr int NCH = KT / 32;
    constexpr int XT = W / BCOLS;
    constexpr int HA = (MODE == 0) ? H : H / 2;
    constexpr int WA = (MODE == 0) ? W : W / 2;
    constexpr bool HASB = (SEG * CAP < KT);
    constexpr bool RGUARD = (H % BROWS) != 0;       // pad rows exist
    constexpr int AE = SEG * CAP / 32;              // A-region end (chunks)
    constexpr int C32 = CAP / 32;                   // A-segment run length
    constexpr int B32 = HASB ? CBP / 32 : 1;        // B-segment run length

    __shared__ __align__(16) ushort lds[2 * PERBUF];

    const int tid = threadIdx.x;

    // ---- chunked XCD swizzle (tot % 8 == 0 for all launches): oc slowest
    const int GX = gridDim.x, GY = gridDim.y, GZ = gridDim.z;
    const int L = blockIdx.x + GX * (blockIdx.y + GY * blockIdx.z);
    const int cpx = (GX * GY * GZ) >> 3;
    const int wsw = (L & 7) * cpx + (L >> 3);
    const int bky = wsw / (GX * GZ);
    const int rem = wsw - bky * (GX * GZ);
    const int bkz = rem / GX;
    const int bkx = rem - bkz * GX;

    const int b = bkz / KS, sid = bkz % KS;
    const int oc0 = bky * NOC;
    const int y0 = (bkx / XT) * BROWS;
    const int x0 = (bkx % XT) * BCOLS;
    const int lane = tid & 63, wv = tid >> 6;
    const int wr = wv / WC, wc = wv % WC;
    const int lq = lane >> 4, ln = lane & 15;
    const int wcb = wc * (WCOLF * 16);
    const int c0 = (sid * NCH) / KS, c1 = ((sid + 1) * NCH) / KS;
    const int wbv = wv * 512;                       // wave slot base (ushorts)

    // ---- A staging geometry (k-independent, source-permuted by swizzle) ----
    const ushort* pAp[NSA]; const ushort* pBp[NSA]; int aKO[NSA];
    for (int s = 0; s < NSA; ++s) {
        const int u = tid + s * 256;
        const int pp = u >> 2, sl = u & 3;
        aKO[s] = (sl ^ ((pp >> 1) & 3)) * 8;        // pre-swizzled k-group
        const bool val = pp < NPX;
        const int ppc = val ? pp : 0;
        const int py = ppc / PW, px = ppc - py * PW;
        int y = y0 + py - 1, x = x0 + px - 1;
        if (MODE == 0) { y = min(max(y, 0), H - 1); x = min(max(x, 0), W - 1); }
        else { y = (y < 0) ? -y : ((y >= H) ? 2 * H - 2 - y : y);
               x = (x < 0) ? -x : ((x >= W) ? 2 * W - 2 - x : x); }
        const int ya = (MODE == 0) ? y : (y >> 1);
        const int xa = (MODE == 0) ? x : (x >> 1);
        bool okA = val, okB = val;
        if (MODE == 2) {
            const float cm = cam[((size_t)b * H + y) * W + x];
            const float um = upm[((size_t)b * HA + ya) * WA + xa];
            okA = okA && (um * cm != 0.f);
            okB = okB && (cm != 0.f);
        }
        pAp[s] = okA ? xA + (size_t)((b * HA + ya) * WA + xa) * ASTR : zpad;
        if constexpr (HASB)
            pBp[s] = okB ? xB + (size_t)((b * H + y) * W + x) * BSTR : zpad;
        else
            pBp[s] = zpad;
    }
    // ---- W staging geometry ----
    const ushort* pWp[NSW];
    for (int s = 0; s < NSW; ++s) {
        const int u = tid + s * 256;
        const int wrow = u >> 2, sl = u & 3;
        const int kg = sl ^ ((wrow >> 1) & 3);      // pre-swizzled k-group
        const int t = wrow / NOC, ocl = wrow - t * NOC;  // true modulo
        pWp[s] = (u < NWU) ?
            wgt + (size_t)(t * OCP + oc0 + ocl) * KT + kg * 8 : zpad;
    }

    // ---- running per-slot source pointers (affine in kc within runs) ----
    const ushort* pa[NSA]; const ushort* pw[NSW];
    auto rebase = [&](int kc) {
        const int ko = kc * 32;
#pragma unroll
        for (int s = 0; s < NSA; ++s) {
            const int k = ko + aKO[s];
            if (!HASB || k < SEG * CAP) {
                int ka = (SEG == 3 && k >= 2 * CAP) ? k - 2 * CAP : k;
                const int pl = (ka >= CAP) ? 1 : 0;
                pa[s] = pAp[s] + pl * APLSTR + AOFF + (ka - pl * CAP);
            } else {
                int kb = k - SEG * CAP;
                if (SEG == 3 && kb >= 2 * CBP) kb -= 2 * CBP;
                pa[s] = pBp[s] + kb;
            }
        }
#pragma unroll
        for (int s = 0; s < NSW; ++s) pw[s] = pWp[s] + ko;
    };
    auto nextb = [&](int kc) {
        if (kc < AE) return (kc / C32 + 1) * C32;          // <= AE always
        return AE + ((kc - AE) / B32 + 1) * B32;
    };
    int ksn = c0;
    rebase(ksn);
    int nb = nextb(ksn);
    auto advance = [&]() {
        ++ksn;
        if (ksn >= c1) return;
        if (ksn == nb) { rebase(ksn); nb = nextb(ksn); }
        else {
#pragma unroll
            for (int s = 0; s < NSA; ++s) pa[s] += 32;
#pragma unroll
            for (int s = 0; s < NSW; ++s) pw[s] += 32;
        }
    };
    auto stageP = [&](int buf) {
        ushort* ab = lds + buf * PERBUF;
        ushort* wb = ab + ASL * 8;
#pragma unroll
        for (int s = 0; s < NSA; ++s)
            if (s * 256 + wv * 64 < NAU)            // wave-uniform skip
                gl_lds16(pa[s], ab + s * 2048 + wbv);
#pragma unroll
        for (int s = 0; s < NSW; ++s)
            if (s * 256 + wv * 64 < NWU)            // wave-uniform skip
                gl_lds16(pw[s], wb + s * 2048 + wbv);
    };

    f32x4 acc[WROWS][WCOLF][NOCF];
#pragma unroll
    for (int i = 0; i < WROWS; ++i)
#pragma unroll
        for (int c = 0; c < WCOLF; ++c)
#pragma unroll
            for (int n = 0; n < NOCF; ++n) acc[i][c][n] = {0.f, 0.f, 0.f, 0.f};

    if (ACCIN) {
#pragma unroll
        for (int ri = 0; ri < WROWS; ++ri) {
            const int yy = y0 + wr * WROWS + ri;
            if (RGUARD && yy >= H) continue;        // pad row: keep acc 0
            const float* Pr = outp +
                ((((size_t)sid * 4 + b) * H + yy) * W + x0 + wcb) * OCP;
#pragma unroll
            for (int cf = 0; cf < WCOLF; ++cf)
#pragma unroll
                for (int n2 = 0; n2 < NOCF; ++n2)
#pragma unroll
                    for (int r = 0; r < 4; ++r)
                        acc[ri][cf][n2][r] =
                            Pr[(size_t)(cf * 16 + lq * 4 + r) * OCP + oc0 + n2 * 16 + ln];
        }
    }

    stageP(0);
    advance();
    __syncthreads();                                 // vmcnt drain: buf0 ready
    int cur = 0;
    for (int kc = c0; kc < c1; ++kc) {
        if (kc + 1 < c1) { stageP(cur ^ 1); advance(); }  // async into other buf
        const ushort* at = lds + cur * PERBUF;
        const ushort* wt = at + ASL * 8;
        // ---- preload A fragments (swizzled reads, conflict-free) ----
        s16x8 afr[WROWS + 2][WCOLF][3];
#pragma unroll
        for (int ar = 0; ar < WROWS + 2; ++ar)
#pragma unroll
            for (int cf = 0; cf < WCOLF; ++cf)
#pragma unroll
                for (int dx = 0; dx < 3; ++dx) {
                    const int p = (wr * WROWS + ar) * PW + wcb + cf * 16 + ln + dx;
                    afr[ar][cf][dx] = *(const s16x8*)
                        &at[p * 32 + ((lq ^ ((p >> 1) & 3)) * 8)];
                }
        // ---- 9 taps ----
#pragma unroll
        for (int t = 0; t < 9; ++t) {
            const int dy = t / 3, dx = t - dy * 3;
#pragma unroll
            for (int n2 = 0; n2 < NOCF; ++n2) {
                const int wrow = t * NOC + n2 * 16 + ln;
                const s16x8 bw = *(const s16x8*)
                    &wt[wrow * 32 + ((lq ^ ((wrow >> 1) & 3)) * 8)];
#pragma unroll
                for (int ri = 0; ri < WROWS; ++ri)
#pragma unroll
                    for (int cf = 0; cf < WCOLF; ++cf)
                        acc[ri][cf][n2] = __builtin_amdgcn_mfma_f32_16x16x32_bf16(
                            afr[ri + dy][cf][dx], bw, acc[ri][cf][n2], 0, 0, 0);
            }
        }
        __syncthreads();   // drains lgkm (reads done) + vmcnt (next buf staged)
        cur ^= 1;
    }

    // ---- epilogue ----
    if (KS > 1) {
#pragma unroll
        for (int ri = 0; ri < WROWS; ++ri) {
            const int yy = y0 + wr * WROWS + ri;
            if (RGUARD && yy >= H) continue;        // pad row: discard
            float* Pr = outp +
                ((((size_t)sid * 4 + b) * H + yy) * W + x0 + wcb) * OCP;
#pragma unroll
            for (int cf = 0; cf < WCOLF; ++cf)
#pragma unroll
                for (int n2 = 0; n2 < NOCF; ++n2)
#pragma unroll
                    for (int r = 0; r < 4; ++r)
                        Pr[(size_t)(cf * 16 + lq * 4 + r) * OCP + oc0 + n2 * 16 + ln] =
                            acc[ri][cf][n2][r];
        }
    } else {
        constexpr int OST = SOUT ? 2 * OCP : OCP;
#pragma unroll
        for (int ri = 0; ri < WROWS; ++ri) {
            const int y = y0 + wr * WROWS + ri;
            if (RGUARD && y >= H) continue;
#pragma unroll
            for (int cf = 0; cf < WCOLF; ++cf)
#pragma unroll
                for (int n2 = 0; n2 < NOCF; ++n2) {
                    const int oc = oc0 + n2 * 16 + ln;
                    const float bv = (oc < OC) ? bias[oc] : 0.f;
#pragma unroll
                    for (int r = 0; r < 4; ++r) {
                        const int x = x0 + wcb + cf * 16 + lq * 4 + r;
                        float v = acc[ri][cf][n2][r] + bv;
                        v = v > 0.f ? v : 0.2f * v;
                        v *= wvm[((size_t)b * H + y) * W + x];
                        if (oc >= OC) v = 0.f;
                        const size_t o = (((size_t)b * H + y) * W + x) * OST + oc;
                        const ushort h = f2bf(v);
                        outb[o] = h;
                        if constexpr (SOUT) outb[o + OCP] = f2bf(v - bf2f(h));
                    }
                }
        }
    }
}

// ---- split-K reduce: sum fp32 partials, bias(+leaky), bf16 hi/lo store ----
template<int KS, int HP, int H, int W, int OCP, bool ACT>
__global__ __launch_bounds__(256)
void reduce_k(const float* __restrict__ P, const float* __restrict__ bias,
              ushort* __restrict__ out, int OC)
{
    constexpr int OG = OCP / 4;
    const int u = blockIdx.x * 256 + threadIdx.x;
    if (u >= 4 * H * W * OG) return;
    const int og = u % OG;
    const int px = u / OG;
    const int x = px % W, y = (px / W) % H, b = px / (W * H);
    float4 s = {0.f, 0.f, 0.f, 0.f};
    for (int sid = 0; sid < KS; ++sid) {
        const float4 v = *(const float4*)
            (P + ((((size_t)sid * 4 + b) * HP + y) * W + x) * OCP + og * 4);
        s.x += v.x; s.y += v.y; s.z += v.z; s.w += v.w;
    }
    const int oc = og * 4;
    const float vv[4] = {s.x, s.y, s.z, s.w};
    ushort hi[4], lo[4];
#pragma unroll
    for (int j = 0; j < 4; ++j) {
        float v = (oc + j < OC) ? vv[j] + bias[oc + j] : 0.f;
        if (ACT) v = v > 0.f ? v : 0.2f * v;
        const ushort h = f2bf(v);
        hi[j] = h;
        lo[j] = f2bf(v - bf2f(h));
    }
    const size_t o = (size_t)px * 2 * OCP + oc;
    *(uint2*)(out + o) = *(uint2*)hi;
    *(uint2*)(out + o + OCP) = *(uint2*)lo;
}

// ---- wave weight repack: wh[3][C][9](+wll[C][9]) -> Wv[t][CP][4] fp32 ----
__global__ __launch_bounds__(256)
void repack_wv_k(const float* __restrict__ wh, const float* __restrict__ wll,
                 float* __restrict__ out, int C, int CP)
{
    const int u = blockIdx.x * 256 + threadIdx.x;
    if (u >= 9 * CP) return;
    const int t = u / CP, ic = u - t * CP;
    float4 v = {0.f, 0.f, 0.f, 0.f};
    if (ic < C) {
        v.x = wh[((size_t)0 * C + ic) * 9 + t];
        v.y = wh[((size_t)1 * C + ic) * 9 + t];
        v.z = wh[((size_t)2 * C + ic) * 9 + t];
        if (wll) v.w = wll[(size_t)ic * 9 + t];
    }
    *(float4*)(out + (size_t)u * 4) = v;
}

// ---- wave convs from channel-last bf16 (hi at +0, lo at +LOOFF) ----
template<int G, int CSTR, int LOOFF, int H, int W, bool SIN, bool HAS_LL>
__global__ __launch_bounds__(256)
void wave_cl_k(const ushort* __restrict__ xq, const float* __restrict__ wv,
               const float* __restrict__ bh, const float* __restrict__ bll,
               const float* __restrict__ mhalf, float scale,
               float* __restrict__ outh, float* __restrict__ outll)
{
    const int lane = threadIdx.x & 63;
    const int pix = blockIdx.x * 4 + (threadIdx.x >> 6);
    const int x = pix % W, y = (pix / W) % H, b = pix / (W * H);
    float a0 = 0.f, a1 = 0.f, a2 = 0.f, a3 = 0.f;
    for (int it = lane; it < 9 * G; it += 64) {
        const int t = it / G, g = it - t * G;
        const int dy = t / 3 - 1, dx = t % 3 - 1;
        const int yy = y + dy, xx = x + dx;
        const int yc = min(max(yy, 0), H - 1), xc = min(max(xx, 0), W - 1);
        const bool inr = (yy >= 0) && (yy < H) && (xx >= 0) && (xx < W);
        const size_t base = (((size_t)b * H + yc) * W + xc) * CSTR + g * 8;
        const uint4 hv = *(const uint4*)(xq + base);
        uint4 lv = {0, 0, 0, 0};
        if constexpr (!SIN) lv = *(const uint4*)(xq + base + LOOFF);
        const float4* wp = (const float4*)(wv + ((size_t)t * (G * 8) + g * 8) * 4);
        const uint* hw = (const uint*)&hv;
        const uint* lw = (const uint*)&lv;
#pragma unroll
        for (int j = 0; j < 8; ++j) {
            const uint wd = hw[j >> 1];
            float xf = (j & 1) ? __uint_as_float(wd & 0xFFFF0000u)
                               : __uint_as_float(wd << 16);
            if constexpr (!SIN) {
                const uint wl = lw[j >> 1];
                xf += (j & 1) ? __uint_as_float(wl & 0xFFFF0000u)
                              : __uint_as_float(wl << 16);
            }
            const float xz = inr ? xf : 0.f;
            const float4 w4 = wp[j];
            a0 = fmaf(w4.x, xz, a0);
            a1 = fmaf(w4.y, xz, a1);
            a2 = fmaf(w4.z, xz, a2);
            if constexpr (HAS_LL) a3 = fmaf(w4.w, xf, a3);
        }
    }
#pragma unroll
    for (int o = 1; o < 64; o <<= 1) {
        a0 += __shfl_xor(a0, o);
        a1 += __shfl_xor(a1, o);
        a2 += __shfl_xor(a2, o);
        if constexpr (HAS_LL) a3 += __shfl_xor(a3, o);
    }
    if (lane == 0) {
        float wm = 1.f;
        if (mhalf) wm = mhalf[((size_t)b * (H / 2) + (y >> 1)) * (W / 2) + (x >> 1)];
        const size_t hb = (size_t)b * 3 * H * W + (size_t)y * W + x;
        outh[hb]             = (a0 + bh[0]) * scale * wm;
        outh[hb + H * W]     = (a1 + bh[1]) * scale * wm;
        outh[hb + 2 * H * W] = (a2 + bh[2]) * scale * wm;
        if constexpr (HAS_LL) outll[((size_t)b * H + y) * W + x] = (a3 + bll[0]) * 8.f;
    }
}

// ---- inverse Haar DWT ----
template<int H, int W>
__global__ __launch_bounds__(256)
void idwt_k(const float* __restrict__ ll, const float* __restrict__ h,
            float* __restrict__ out)
{
    const int g = blockIdx.x * 256 + threadIdx.x;
    if (g >= 4 * H * W) return;
    const int x = g % W, y = (g / W) % H, b = g / (W * H);
    const float l  = ll[g];
    const float lh = h[((size_t)(b * 3 + 0) * H + y) * W + x];
    const float hl = h[((size_t)(b * 3 + 1) * H + y) * W + x];
    const float hh = h[((size_t)(b * 3 + 2) * H + y) * W + x];
    const float x00 = (l + lh + hl + hh) * 0.5f;
    const float x01 = (l - lh + hl - hh) * 0.5f;
    const float x10 = (l + lh - hl - hh) * 0.5f;
    const float x11 = (l - lh - hl + hh) * 0.5f;
    float* ob = out + (size_t)b * (2 * H) * (2 * W);
    ob[(size_t)(2 * y) * (2 * W) + 2 * x]         = x00;
    ob[(size_t)(2 * y) * (2 * W) + 2 * x + 1]     = x01;
    ob[(size_t)(2 * y + 1) * (2 * W) + 2 * x]     = x10;
    ob[(size_t)(2 * y + 1) * (2 * W) + 2 * x + 1] = x11;
}

__global__ __launch_bounds__(256)
void minmax_k(const float* __restrict__ p, int n, float* __restrict__ thr)
{
    __shared__ float smax[256], smin[256];
    float mx = -1e30f, mn = 1e30f;
    for (int i = threadIdx.x; i < n; i += 256) {
        const float v = p[i];
        mx = fmaxf(mx, v);
        mn = fminf(mn, v);
    }
    smax[threadIdx.x] = mx;
    smin[threadIdx.x] = mn;
    __syncthreads();
    for (int s = 128; s > 0; s >>= 1) {
        if (threadIdx.x < s) {
            smax[threadIdx.x] = fmaxf(smax[threadIdx.x], smax[threadIdx.x + s]);
            smin[threadIdx.x] = fminf(smin[threadIdx.x], smin[threadIdx.x + s]);
        }
        __syncthreads();
    }
    if (threadIdx.x == 0) *thr = (smax[0] - smin[0]) * 0.1f;
}

template<int H, int W>
__global__ __launch_bounds__(256)
void mask_k(const float* __restrict__ h, const float* __restrict__ thr,
            float* __restrict__ mask)
{
    const int g = blockIdx.x * 256 + threadIdx.x;
    if (g >= 4 * H * W) return;
    const int x = g % W, y = (g / W) % H, b = g / (W * H);
    const float t  = *thr;
    const float v0 = fabsf(h[((size_t)(b * 3 + 0) * H + y) * W + x]);
    const float v1 = fabsf(h[((size_t)(b * 3 + 1) * H + y) * W + x]);
    const float v2 = fabsf(h[((size_t)(b * 3 + 2) * H + y) * W + x]);
    mask[g] = (fmaxf(v0, fmaxf(v1, v2)) > t) ? 1.f : 0.f;
}

template<int H, int W, int R>
__global__ __launch_bounds__(256)
void dilate_k(const float* __restrict__ m, float* __restrict__ o)
{
    const int g = blockIdx.x * 256 + threadIdx.x;
    if (g >= 4 * H * W) return;
    const int x = g % W, y = (g / W) % H, b = g / (W * H);
    float v = 0.f;
    for (int dy = -R; dy <= R; ++dy) {
        const int yy = y + dy;
        if (yy < 0 || yy >= H) continue;
        for (int dx = -R; dx <= R; ++dx) {
            const int xx = x + dx;
            if (xx < 0 || xx >= W) continue;
            v = fmaxf(v, m[((size_t)b * H + yy) * W + xx]);
        }
    }
    o[g] = (v > 0.f) ? 1.f : 0.f;
}

template<int H, int W>
__global__ __launch_bounds__(256)
void masksfull_k(const float* __restrict__ m, float* __restrict__ conva,
                 float* __restrict__ wavem)
{
    const int g = blockIdx.x * 256 + threadIdx.x;
    constexpr int H2 = 2 * H, W2 = 2 * W;
    if (g >= 4 * H2 * W2) return;
    const int x = g % W2, y = (g / W2) % H2, b = g / (W2 * H2);
    float c5 = 0.f, c3 = 0.f;
    for (int dy = -2; dy <= 2; ++dy) {
        const int yy = y + dy;
        if (yy < 0 || yy >= H2) continue;
        const int my = yy >> 1;
        for (int dx = -2; dx <= 2; ++dx) {
            const int xx = x + dx;
            if (xx < 0 || xx >= W2) continue;
            const float v = m[((size_t)b * H + my) * W + (xx >> 1)];
            c5 = fmaxf(c5, v);
            if (dy >= -1 && dy <= 1 && dx >= -1 && dx <= 1) c3 = fmaxf(c3, v);
        }
    }
    conva[g] = (c5 > 0.f) ? 1.f : 0.f;
    wavem[g] = (c3 > 0.f) ? 1.f : 0.f;
}

// ---------------------------------------------------------------------------
// workspace layout (bytes)
// ---------------------------------------------------------------------------
static constexpr size_t WSTEM = 0;             // 66,769,920 (9*1104*3360*2), both phases
static constexpr size_t WUP1  = 0;             // 46,780,416 (9*576*4512*2)
static constexpr size_t X16   = 46780416ull;   // 7,864,320
static constexpr size_t WUP2  = 54644736ull;   // 11,943,936 (9*288*2304*2) end 66,588,672
static constexpr size_t XB    = 0ull;          // 23,592,960 (over WUP1, dead)
static constexpr size_t X4    = 23592960ull;   // 15,728,640 (over WUP1, dead) end 39,321,600
static constexpr size_t WUP3  = 66769920ull;   // 995,328  (over X32, dead)
static constexpr size_t WV1   = 67765248ull;   // 79,488
static constexpr size_t WV2   = 67844736ull;   // 40,320
static constexpr size_t WV3   = 67885056ull;   // 20,736 end 67,905,792
static constexpr size_t X32   = 66769920ull;   // 11,304,960 end 78,074,880
static constexpr size_t XD0   = 78074880ull;   // 5,652,480  end 83,727,360
static constexpr size_t ZPADO = 83727360ull;   // 16,384 zero page (A/W redirect + X32 tail guard)
static constexpr size_t PF    = 83743744ull;   // stem P 22.6M / up1 P 23.6M (H-stride, compact)
static constexpr size_t XAOF  = 83743744ull;   // 23,592,960 end 107,336,704
static constexpr size_t XD1   = 110859264ull;  // 11,796,480 end 122,655,744
static constexpr size_t X8    = 122655744ull;  // 15,728,640 end 138,384,384
static constexpr size_t F32B  = 138384384ull;
static constexpr size_t O_LL1 = 0, O_H1 = 5120, O_LLB = 20480, O_H2 = 40960;
static constexpr size_t O_LLC = 102400, O_H3 = 184320, O_M1 = 430080;
static constexpr size_t O_UPM1 = 435200, O_CAM1 = 440320, O_WM1 = 460800;
static constexpr size_t O_M2 = 481280, O_UPM2 = 501760, O_CAM2 = 522240;
static constexpr size_t O_WM2 = 604160, O_RED = 686080;

extern "C" void kernel_launch(void* const* d_in, const int* in_sizes, int n_in,
                              void* d_out, int out_size, void* d_ws, size_t ws_size,
                              hipStream_t stream)
{
    const float* x32     = (const float*)d_in[0];
    const float* x16     = (const float*)d_in[1];
    const float* x8      = (const float*)d_in[2];
    const float* x4      = (const float*)d_in[3];
    const float* conv2_w = (const float*)d_in[4];
    const float* conv2_b = (const float*)d_in[5];
    const float* up1_w   = (const float*)d_in[6];
    const float* up1_b   = (const float*)d_in[7];
    const float* w1ll_w  = (const float*)d_in[8];
    const float* w1ll_b  = (const float*)d_in[9];
    const float* w1_w    = (const float*)d_in[10];
    const float* w1_b    = (const float*)d_in[11];
    const float* up2_w   = (const float*)d_in[12];
    const float* up2_b   = (const float*)d_in[13];
    const float* w2_w    = (const float*)d_in[14];
    const float* w2_b    = (const float*)d_in[15];
    const float* up3_w   = (const float*)d_in[16];
    const float* up3_b   = (const float*)d_in[17];
    const float* w3_w    = (const float*)d_in[18];
    const float* w3_b    = (const float*)d_in[19];

    char* ws = (char*)d_ws;
    auto U = [&](size_t off) { return (ushort*)(ws + off); };
    float* Pf  = (float*)(ws + PF);
    float* f32 = (float*)(ws + F32B);
    float* ll1   = f32 + O_LL1;
    float* h1    = f32 + O_H1;
    float* llb   = f32 + O_LLB;
    float* h2    = f32 + O_H2;
    float* llc   = f32 + O_LLC;
    float* h3    = f32 + O_H3;
    float* mask1 = f32 + O_M1;
    float* upm1  = f32 + O_UPM1;
    float* cam1  = f32 + O_CAM1;
    float* wm1   = f32 + O_WM1;
    float* mask2 = f32 + O_M2;
    float* upm2  = f32 + O_UPM2;
    float* cam2  = f32 + O_CAM2;
    float* wm2   = f32 + O_WM2;
    float* wv1   = (float*)(ws + WV1);
    float* wv2   = (float*)(ws + WV2);
    float* wv3   = (float*)(ws + WV3);
    const ushort* zp = U(ZPADO);

    // ---- zero page + XD0 head guard ----
    zero_k<<<1, 256, 0, stream>>>(U(ZPADO), U(XD0));

    // ---- stem: 2 IC-phases, split-K 4; tile 4x32, NOC48 ----
    repack_x_k<true><<<dim3(5, 69, 4), 256, 0, stream>>>(x32, U(X32), 2208, 320, 4416, 2208);
    repack_w_k<<<1812, 256, 0, stream>>>(conv2_w, U(WSTEM), 1104, 2208, 0, 1104, 1120, 0, 0, 8, 3, 1104, 3360);
    conv_async_k<0, 2, 2, 2, 1, 3, 10, 32, 1104, 3360, 1120, 8, 3, 4416, 2208, 0, 1, 4, 2, false, false>
        <<<dim3(3, 23, 16), 256, 0, stream>>>(U(X32), nullptr, U(WSTEM), nullptr,
            nullptr, nullptr, nullptr, zp, nullptr, Pf, 1104);
    repack_w_k<<<1812, 256, 0, stream>>>(conv2_w, U(WSTEM), 1104, 2208, 1104, 1104, 1120, 0, 0, 8, 3, 1104, 3360);
    conv_async_k<0, 2, 2, 2, 1, 3, 10, 32, 1104, 3360, 1120, 8, 3, 4416, 2208, 1104, 1, 4, 2, false, true>
        <<<dim3(3, 23, 16), 256, 0, stream>>>(U(X32), nullptr, U(WSTEM), nullptr,
            nullptr, nullptr, nullptr, zp, nullptr, Pf, 1104);
    reduce_k<4, 10, 10, 32, 1104, false><<<1380, 256, 0, stream>>>(Pf, conv2_b, U(XD0), 1104);
    // ---- phase B repacks ----
    repack_w_k<<<1269, 256, 0, stream>>>(up1_w, U(WUP1), 552, 1488, 0, 1104, 1120, 1104, 384, 384, 3, 576, 4512);
    repack_x_k<true><<<dim3(20, 12, 4), 256, 0, stream>>>(x16, U(X16), 384, 1280, 768, 384);
    repack_w_k<<<324, 256, 0, stream>>>(up2_w, U(WUP2), 276, 744, 0, 552, 576, 552, 192, 192, 3, 288, 2304);
    repack_w_k<<<27, 256, 0, stream>>>(up3_w, U(WUP3), 138, 372, 0, 276, 288, 276, 96, 96, 1, 144, 384);
    repack_x_k<true><<<dim3(80, 6, 4), 256, 0, stream>>>(x8, U(X8), 192, 5120, 384, 192);
    repack_wv_k<<<20, 256, 0, stream>>>(w1_w, w1ll_w, wv1, 552, 552);
    repack_wv_k<<<10, 256, 0, stream>>>(w2_w, nullptr, wv2, 276, 280);
    repack_wv_k<<<6, 256, 0, stream>>>(w3_w, nullptr, wv3, 138, 144);
    // ---- up1 (split-K 2; tile 8x32, NOC32; rows 20-23 guarded) ----
    conv_async_k<1, 2, 2, 4, 1, 2, 20, 64, 576, 4512, 1120, 384, 3, 2208, 1104, 0, 768, 2, 2, false, false>
        <<<dim3(6, 18, 8), 256, 0, stream>>>(U(XD0), U(X16), U(WUP1), nullptr,
            nullptr, nullptr, nullptr, zp, nullptr, Pf, 552);
    reduce_k<2, 20, 20, 64, 576, true><<<2880, 256, 0, stream>>>(Pf, up1_b, U(XD1), 552);
    repack_x_k<false><<<dim3(320, 3, 4), 256, 0, stream>>>(x4, U(X4), 96, 20480, 96, 0);
    // ---- wave1 + level-1 masks ----
    wave_cl_k<69, 1152, 576, 20, 64, false, true><<<1280, 256, 0, stream>>>(
        U(XD1), wv1, w1_b, w1ll_b, nullptr, 4.f, h1, ll1);
    idwt_k<20, 64><<<20, 256, 0, stream>>>(ll1, h1, llb);
    minmax_k<<<1, 256, 0, stream>>>(llb, 20480, f32 + O_RED);
    mask_k<20, 64><<<20, 256, 0, stream>>>(h1, f32 + O_RED, mask1);
    dilate_k<20, 64, 2><<<20, 256, 0, stream>>>(mask1, upm1);
    masksfull_k<20, 64><<<80, 256, 0, stream>>>(mask1, cam1, wm1);
    // ---- up2 (tile 8x32, NOC32, masked) ----
    conv_async_k<2, 2, 2, 4, 1, 2, 40, 128, 288, 2304, 576, 192, 3, 1152, 576, 0, 384, 1, 2, true, false>
        <<<dim3(20, 9, 4), 256, 0, stream>>>(U(XD1), U(X8), U(WUP2), up2_b,
            upm1, cam1, wm1, zp, U(XAOF), nullptr, 276);
    // ---- wave2 + level-0 masks ----
    wave_cl_k<35, 576, 288, 40, 128, false, false><<<5120, 256, 0, stream>>>(
        U(XAOF), wv2, w2_b, nullptr, mask1, 2.f, h2, nullptr);
    idwt_k<40, 128><<<80, 256, 0, stream>>>(llb, h2, llc);
    minmax_k<<<1, 256, 0, stream>>>(llc, 81920, f32 + O_RED + 1);
    mask_k<40, 128><<<80, 256, 0, stream>>>(h2, f32 + O_RED + 1, mask2);
    dilate_k<40, 128, 2><<<80, 256, 0, stream>>>(mask2, upm2);
    masksfull_k<40, 128><<<320, 256, 0, stream>>>(mask2, cam2, wm2);
    // ---- up3 (single bf16; tile 8x32, NOC16, 2 blk/CU, masked) ----
    conv_async_k<2, 2, 2, 4, 1, 1, 80, 256, 144, 384, 288, 96, 1, 576, 288, 0, 96, 1, 2, false, false>
        <<<dim3(80, 9, 4), 256, 0, stream>>>(U(XAOF), U(X4), U(WUP3), up3_b,
            upm2, cam2, wm2, zp, U(XB), nullptr, 138);
    // ---- wave3 + final idwt ----
    wave_cl_k<18, 144, 0, 80, 256, true, false><<<20480, 256, 0, stream>>>(
        U(XB), wv3, w3_b, nullptr, mask2, 1.f, h3, nullptr);
    idwt_k<80, 256><<<320, 256, 0, stream>>>(llc, h3, (float*)d_out);
}